// Round 1
// baseline (382.985 us; speedup 1.0000x reference)
//
#include <hip/hip_runtime.h>

// ---------------------------------------------------------------------------
// MultiHeadAttention forward, MI355X/gfx950.
// B=2, T=2048, D=2048, H=16, Dh=128. fp32 in/out, bf16 MFMA internally.
// Reference quirks (faithful): multiplicative tril mask (masked scores = 0,
// NOT -inf -> they contribute exp(0)=1 to a softmax over ALL 2048 cols),
// scale = 1/sqrt(T).
// ---------------------------------------------------------------------------

typedef __attribute__((ext_vector_type(4))) float  f32x4;
typedef __attribute__((ext_vector_type(8))) short  bf16x8;
typedef __attribute__((ext_vector_type(4))) unsigned short u16x4;

#define AS1 __attribute__((address_space(1)))
#define AS3 __attribute__((address_space(3)))

__device__ __forceinline__ void llds16(const void* g, void* l) {
  __builtin_amdgcn_global_load_lds((const AS1 void*)g, (AS3 void*)l, 16, 0, 0);
}

__device__ __forceinline__ unsigned short f2bf(float f) {
  unsigned int u = __builtin_bit_cast(unsigned int, f);
  u += 0x7fffu + ((u >> 16) & 1u);   // RNE
  return (unsigned short)(u >> 16);
}

// ---------------------------------------------------------------------------
// cast x (fp32) -> bf16, 4 elements/thread
// ---------------------------------------------------------------------------
__global__ __launch_bounds__(256) void cast_x_kernel(const float* __restrict__ in,
                                                     unsigned short* __restrict__ out) {
  int i = blockIdx.x * 256 + threadIdx.x;
  f32x4 v = ((const f32x4*)in)[i];
  u16x4 o;
  o[0] = f2bf(v[0]); o[1] = f2bf(v[1]); o[2] = f2bf(v[2]); o[3] = f2bf(v[3]);
  ((u16x4*)out)[i] = o;
}

// ---------------------------------------------------------------------------
// W [2048][2048] fp32 -> Wt [n][k] bf16  (Wt[n][k] = W[k][n])
// ---------------------------------------------------------------------------
__global__ __launch_bounds__(256) void transpose_w_kernel(const float* __restrict__ W,
                                                          unsigned short* __restrict__ Wt) {
  __shared__ float tile[32][33];
  const int bx = blockIdx.x << 5;   // k base
  const int by = blockIdx.y << 5;   // n base
  const int tx = threadIdx.x;       // 0..31
  const int ty = threadIdx.y;       // 0..7
#pragma unroll
  for (int r = ty; r < 32; r += 8)
    tile[r][tx] = W[(size_t)(bx + r) * 2048 + by + tx];
  __syncthreads();
#pragma unroll
  for (int r = ty; r < 32; r += 8)
    Wt[(size_t)(by + r) * 2048 + bx + tx] = f2bf(tile[tx][r]);
}

// ---------------------------------------------------------------------------
// bf16 GEMM, C[M][N] = A[M][K] @ Bt[N][K]^T.  M=4096(or any mult of 128),
// N=2048, K=2048. 128x128 tile, BK=32, 4 waves (2x2), 16x16x32 MFMA.
// LDS XOR-swizzled (64B rows, slot ^= (row>>1)&3) on BOTH sides:
// pre-swizzled global source for global_load_lds + swizzled ds_read.
// OUT: 0 = bf16 row-major, 1 = bf16 scattered as Vt[(b*16+h)*128+d][t],
//      2 = fp32 row-major.
// ---------------------------------------------------------------------------
template <int OUT>
__global__ __launch_bounds__(256) void gemm_bt(const unsigned short* __restrict__ A,
                                               const unsigned short* __restrict__ Bt,
                                               void* __restrict__ Cv) {
  __shared__ __align__(16) char smem[16384];    // A tile 8K | B tile 8K
  const int tid  = threadIdx.x;
  const int lane = tid & 63;
  const int w    = tid >> 6;
  const int bn = blockIdx.x, bm = blockIdx.y;
  const int wr = w >> 1, wc = w & 1;
  const int q16 = lane >> 4;
  const int l15 = lane & 15;

  f32x4 acc[4][4];
#pragma unroll
  for (int i = 0; i < 4; ++i)
#pragma unroll
    for (int j = 0; j < 4; ++j) acc[i][j] = (f32x4){0.f, 0.f, 0.f, 0.f};

  for (int k0 = 0; k0 < 2048; k0 += 32) {
    __syncthreads();
    // stage: each wave 2 chunks of 1024B for A and for B.
    // linear LDS offset o = ch*1024 + lane*16 -> row = ch*16 + lane/4,
    // physical in-row byte wb = (lane&3)*16; logical col = wb ^ swz(row).
#pragma unroll
    for (int c = 0; c < 2; ++c) {
      int ch  = (w << 1) + c;
      int row = (ch << 4) + (lane >> 2);
      int colb = ((lane & 3) << 4) ^ (((row >> 1) & 3) << 4);
      const unsigned short* srcA = A + (size_t)((bm << 7) + row) * 2048 + k0 + (colb >> 1);
      llds16(srcA, smem + (ch << 10));
      const unsigned short* srcB = Bt + (size_t)((bn << 7) + row) * 2048 + k0 + (colb >> 1);
      llds16(srcB, smem + 8192 + (ch << 10));
    }
    asm volatile("s_waitcnt vmcnt(0)" ::: "memory");
    __syncthreads();

    bf16x8 af[4], bf[4];
#pragma unroll
    for (int mi = 0; mi < 4; ++mi) {
      int row = (wr << 6) + (mi << 4) + l15;
      af[mi] = *(const bf16x8*)(smem + (row << 6) + ((q16 << 4) ^ (((row >> 1) & 3) << 4)));
    }
#pragma unroll
    for (int ni = 0; ni < 4; ++ni) {
      int row = (wc << 6) + (ni << 4) + l15;
      bf[ni] = *(const bf16x8*)(smem + 8192 + (row << 6) + ((q16 << 4) ^ (((row >> 1) & 3) << 4)));
    }
#pragma unroll
    for (int mi = 0; mi < 4; ++mi)
#pragma unroll
      for (int ni = 0; ni < 4; ++ni)
        acc[mi][ni] = __builtin_amdgcn_mfma_f32_16x16x32_bf16(af[mi], bf[ni], acc[mi][ni], 0, 0, 0);
  }

  // epilogue. C/D layout: col = lane&15, row = (lane>>4)*4 + reg  [m89]
  const int rb = q16 << 2;
#pragma unroll
  for (int mi = 0; mi < 4; ++mi) {
    int m0 = (bm << 7) + (wr << 6) + (mi << 4) + rb;
#pragma unroll
    for (int ni = 0; ni < 4; ++ni) {
      int n = (bn << 7) + (wc << 6) + (ni << 4) + l15;
      if constexpr (OUT == 0) {
        unsigned short* C = (unsigned short*)Cv;
#pragma unroll
        for (int j = 0; j < 4; ++j)
          C[(size_t)(m0 + j) * 2048 + n] = f2bf(acc[mi][ni][j]);
      } else if constexpr (OUT == 1) {
        // V^T scatter: Vt[((b*16 + n/128)*128 + n%128)*2048 + t], t = m%2048.
        // the 4 regs are 4 consecutive t -> one 8B packed store.
        u16x4 pk;
#pragma unroll
        for (int j = 0; j < 4; ++j) pk[j] = f2bf(acc[mi][ni][j]);
        int b = m0 >> 11, t = m0 & 2047;
        unsigned short* C = (unsigned short*)Cv;
        *(u16x4*)(C + ((size_t)((b << 4) + (n >> 7)) * 128 + (n & 127)) * 2048 + t) = pk;
      } else {
        float* C = (float*)Cv;
#pragma unroll
        for (int j = 0; j < 4; ++j)
          C[(size_t)(m0 + j) * 2048 + n] = acc[mi][ni][j];
      }
    }
  }
}

// ---------------------------------------------------------------------------
// Fused attention. Grid (32 q-tiles, 32 bh). Block = 4 waves; each wave owns
// 16 q-rows. Per 32-s step: stage K tile [32][128] + Vt tile [128][32] into
// swizzled LDS, QK^T (8 MFMA), score = (s<=t ? raw*scale : 0), p = exp(score)
// (no max-subtract needed: |score| <~ 1.5), row-sum via 16-lane butterfly,
// P -> per-wave LDS (bf16) -> A-fragment, PV (8 MFMA). Epilogue: O = acc/ell.
// ---------------------------------------------------------------------------
__global__ __launch_bounds__(256) void attn_kernel(const unsigned short* __restrict__ Q,
                                                   const unsigned short* __restrict__ K,
                                                   const unsigned short* __restrict__ V,  // Vt layout
                                                   unsigned short* __restrict__ O) {
  __shared__ __align__(16) char smem[20480];  // K 8K | V 8K | P 4x1K
  const int tid  = threadIdx.x;
  const int lane = tid & 63;
  const int w    = tid >> 6;
  const int q16  = lane >> 4;
  const int l15  = lane & 15;
  const int bh = blockIdx.y;
  const int b  = bh >> 4;
  const int t0 = (blockIdx.x << 6) + (w << 4);
  const float scale = 0.02209708691207961f;   // 1/sqrt(2048)

  const size_t qkbase = ((size_t)(b << 11)) * 2048 + ((size_t)(bh & 15) << 7);

  // Q fragments: lane holds Q[t0 + (lane&15)][8*(lane>>4) + j + 32*kk]
  bf16x8 qf[4];
  {
    const unsigned short* qp = Q + qkbase + (size_t)(t0 + l15) * 2048 + (q16 << 3);
#pragma unroll
    for (int kk = 0; kk < 4; ++kk) qf[kk] = *(const bf16x8*)(qp + (kk << 5));
  }

  f32x4 oacc[8];
#pragma unroll
  for (int i = 0; i < 8; ++i) oacc[i] = (f32x4){0.f, 0.f, 0.f, 0.f};
  float ell[4] = {0.f, 0.f, 0.f, 0.f};
  const int rb = q16 << 2;

  for (int s0 = 0; s0 < 2048; s0 += 32) {
    __syncthreads();
    // stage K tile: [32 rows s][256B], swz: col ^= (row&7)<<4
#pragma unroll
    for (int c = 0; c < 2; ++c) {
      int ch  = (w << 1) + c;
      int row = (ch << 2) + q16;                       // 4 rows / 1KB chunk
      int colb = (l15 << 4) ^ ((row & 7) << 4);
      const unsigned short* src = K + qkbase + (size_t)(s0 + row) * 2048 + (colb >> 1);
      llds16(src, smem + (ch << 10));
    }
    // stage Vt tile: [128 rows d][64B], swz: col ^= ((row>>2)&3)<<4
#pragma unroll
    for (int c = 0; c < 2; ++c) {
      int ch  = (w << 1) + c;
      int row = (ch << 4) + (lane >> 2);               // 16 rows / 1KB chunk
      int colb = ((lane & 3) << 4) ^ (((row >> 2) & 3) << 4);
      const unsigned short* src = V + (size_t)((bh << 7) + row) * 2048 + s0 + (colb >> 1);
      llds16(src, smem + 8192 + (ch << 10));
    }
    asm volatile("s_waitcnt vmcnt(0)" ::: "memory");
    __syncthreads();

    // QK^T: two 16-col s-tiles
    f32x4 sA = (f32x4){0.f, 0.f, 0.f, 0.f}, sB = (f32x4){0.f, 0.f, 0.f, 0.f};
#pragma unroll
    for (int kk = 0; kk < 4; ++kk) {
      int r0 = l15;
      bf16x8 k0f = *(const bf16x8*)(smem + (r0 << 8) + (((kk << 6) + (q16 << 4)) ^ ((r0 & 7) << 4)));
      sA = __builtin_amdgcn_mfma_f32_16x16x32_bf16(qf[kk], k0f, sA, 0, 0, 0);
      int r1 = 16 + l15;
      bf16x8 k1f = *(const bf16x8*)(smem + (r1 << 8) + (((kk << 6) + (q16 << 4)) ^ ((r1 & 7) << 4)));
      sB = __builtin_amdgcn_mfma_f32_16x16x32_bf16(qf[kk], k1f, sB, 0, 0, 0);
    }

    // scores -> p = exp(masked*scale); masked (s>t) -> exp(0) = 1 (reference!)
    float pA[4], pB[4];
    float rs[4];
#pragma unroll
    for (int j = 0; j < 4; ++j) {
      int t  = t0 + rb + j;
      int sa = s0 + l15;
      float vA = (sa <= t)      ? sA[j] * scale : 0.f;
      float vB = (sa + 16 <= t) ? sB[j] * scale : 0.f;
      pA[j] = __expf(vA);
      pB[j] = __expf(vB);
      rs[j] = pA[j] + pB[j];
    }
#pragma unroll
    for (int j = 0; j < 4; ++j) {
      float r = rs[j];
      r += __shfl_xor(r, 1, 64);
      r += __shfl_xor(r, 2, 64);
      r += __shfl_xor(r, 4, 64);
      r += __shfl_xor(r, 8, 64);
      ell[j] += r;
    }

    // P -> per-wave LDS [16 t][32 s] bf16, swz: col ^= ((row>>1)&3)<<4
    char* Psm = smem + 16384 + (w << 10);
#pragma unroll
    for (int j = 0; j < 4; ++j) {
      int r   = rb + j;
      int swz = ((r >> 1) & 3) << 4;
      *(unsigned short*)(Psm + (r << 6) + ((l15 << 1) ^ swz))        = f2bf(pA[j]);
      *(unsigned short*)(Psm + (r << 6) + ((32 + (l15 << 1)) ^ swz)) = f2bf(pB[j]);
    }
    asm volatile("s_waitcnt lgkmcnt(0)" ::: "memory");

    // P A-fragment: lane holds P[lane&15][8*(lane>>4)+j]
    bf16x8 pa;
    {
      int r = l15;
      pa = *(const bf16x8*)(Psm + (r << 6) + ((q16 << 4) ^ (((r >> 1) & 3) << 4)));
    }
    // PV: 8 d-tiles of 16
#pragma unroll
    for (int ni = 0; ni < 8; ++ni) {
      int dr = (ni << 4) + l15;
      bf16x8 vb = *(const bf16x8*)(smem + 8192 + (dr << 6) + ((q16 << 4) ^ (((dr >> 2) & 3) << 4)));
      oacc[ni] = __builtin_amdgcn_mfma_f32_16x16x32_bf16(pa, vb, oacc[ni], 0, 0, 0);
    }
  }

  // epilogue: O[t][h*128+d] = oacc / ell
#pragma unroll
  for (int j = 0; j < 4; ++j) {
    float inv = 1.0f / ell[j];
    int t = t0 + rb + j;
    unsigned short* op = O + qkbase + (size_t)t * 2048;
#pragma unroll
    for (int ni = 0; ni < 8; ++ni)
      op[(ni << 4) + l15] = f2bf(oacc[ni][j] * inv);
  }
}

// ---------------------------------------------------------------------------
// launch
// ---------------------------------------------------------------------------
extern "C" void kernel_launch(void* const* d_in, const int* in_sizes, int n_in,
                              void* d_out, int out_size, void* d_ws, size_t ws_size,
                              hipStream_t stream) {
  (void)in_sizes; (void)n_in; (void)out_size; (void)ws_size;
  const float* x  = (const float*)d_in[0];
  const float* Wq = (const float*)d_in[1];
  const float* Wk = (const float*)d_in[2];
  const float* Wv = (const float*)d_in[3];
  const float* Wo = (const float*)d_in[4];
  float* out = (float*)d_out;

  char* ws = (char*)d_ws;
  unsigned short* Xb  = (unsigned short*)(ws);                        // 16 MiB (reused as O)
  unsigned short* Wqt = (unsigned short*)(ws + 16777216);             // 8 MiB
  unsigned short* Wkt = (unsigned short*)(ws + 16777216 + 8388608);
  unsigned short* Wvt = (unsigned short*)(ws + 16777216 + 2 * 8388608);
  unsigned short* Wot = (unsigned short*)(ws + 16777216 + 3 * 8388608);
  unsigned short* Qb  = (unsigned short*)(ws + 50331648);             // 16 MiB
  unsigned short* Kb  = (unsigned short*)(ws + 67108864);             // 16 MiB
  unsigned short* Vt  = (unsigned short*)(ws + 83886080);             // 16 MiB
  unsigned short* Ob  = Xb;   // X no longer needed after the V projection
  // total ws use: 100,663,296 B

  cast_x_kernel<<<8192, 256, 0, stream>>>(x, Xb);
  {
    dim3 tb(32, 8), tg(64, 64);
    transpose_w_kernel<<<tg, tb, 0, stream>>>(Wq, Wqt);
    transpose_w_kernel<<<tg, tb, 0, stream>>>(Wk, Wkt);
    transpose_w_kernel<<<tg, tb, 0, stream>>>(Wv, Wvt);
    transpose_w_kernel<<<tg, tb, 0, stream>>>(Wo, Wot);
  }
  dim3 gg(16, 32);   // (N/128, M/128)
  gemm_bt<0><<<gg, 256, 0, stream>>>(Xb, Wqt, (void*)Qb);
  gemm_bt<0><<<gg, 256, 0, stream>>>(Xb, Wkt, (void*)Kb);
  gemm_bt<1><<<gg, 256, 0, stream>>>(Xb, Wvt, (void*)Vt);

  attn_kernel<<<dim3(32, 32), 256, 0, stream>>>(Qb, Kb, Vt, Ob);

  gemm_bt<2><<<gg, 256, 0, stream>>>(Ob, Wot, (void*)out);
}

// Round 2
// 330.010 us; speedup vs baseline: 1.1605x; 1.1605x over previous
//
#include <hip/hip_runtime.h>

// ---------------------------------------------------------------------------
// MultiHeadAttention forward, MI355X/gfx950.
// B=2, T=2048, D=2048, H=16, Dh=128. fp32 in/out, bf16 MFMA internally.
// Reference quirks (faithful): multiplicative tril mask (masked scores = 0,
// NOT -inf -> exp(0)=1 contributions over ALL 2048 cols), scale = 1/sqrt(T).
// Round 2: causal skip + V-suffix-sum correction (masked p==1 exactly),
// work-balanced strip pairing, 2-phase pipelined K/V staging.
// ---------------------------------------------------------------------------

typedef __attribute__((ext_vector_type(4))) float  f32x4;
typedef __attribute__((ext_vector_type(8))) short  bf16x8;
typedef __attribute__((ext_vector_type(4))) unsigned short u16x4;

#define AS1 __attribute__((address_space(1)))
#define AS3 __attribute__((address_space(3)))

__device__ __forceinline__ void llds16(const void* g, void* l) {
  __builtin_amdgcn_global_load_lds((const AS1 void*)g, (AS3 void*)l, 16, 0, 0);
}

__device__ __forceinline__ unsigned short f2bf(float f) {
  unsigned int u = __builtin_bit_cast(unsigned int, f);
  u += 0x7fffu + ((u >> 16) & 1u);   // RNE
  return (unsigned short)(u >> 16);
}

__device__ __forceinline__ float bf2f(unsigned short u) {
  return __builtin_bit_cast(float, (unsigned int)u << 16);
}

// ---------------------------------------------------------------------------
// cast x (fp32) -> bf16, 4 elements/thread
// ---------------------------------------------------------------------------
__global__ __launch_bounds__(256) void cast_x_kernel(const float* __restrict__ in,
                                                     unsigned short* __restrict__ out) {
  int i = blockIdx.x * 256 + threadIdx.x;
  f32x4 v = ((const f32x4*)in)[i];
  u16x4 o;
  o[0] = f2bf(v[0]); o[1] = f2bf(v[1]); o[2] = f2bf(v[2]); o[3] = f2bf(v[3]);
  ((u16x4*)out)[i] = o;
}

// ---------------------------------------------------------------------------
// W [2048][2048] fp32 -> Wt [n][k] bf16  (Wt[n][k] = W[k][n])
// ---------------------------------------------------------------------------
__global__ __launch_bounds__(256) void transpose_w_kernel(const float* __restrict__ W,
                                                          unsigned short* __restrict__ Wt) {
  __shared__ float tile[32][33];
  const int bx = blockIdx.x << 5;   // k base
  const int by = blockIdx.y << 5;   // n base
  const int tx = threadIdx.x;       // 0..31
  const int ty = threadIdx.y;       // 0..7
#pragma unroll
  for (int r = ty; r < 32; r += 8)
    tile[r][tx] = W[(size_t)(bx + r) * 2048 + by + tx];
  __syncthreads();
#pragma unroll
  for (int r = ty; r < 32; r += 8)
    Wt[(size_t)(by + r) * 2048 + bx + tx] = f2bf(tile[tx][r]);
}

// ---------------------------------------------------------------------------
// bf16 GEMM, C[M][N] = A[M][K] @ Bt[N][K]^T. 128x128 tile, BK=32, 4 waves,
// 16x16x32 MFMA, both-sides XOR-swizzled LDS + global_load_lds width 16.
// OUT: 0 = bf16 row-major, 1 = bf16 scattered as Vt[(b*16+h)*128+d][t],
//      2 = fp32 row-major.
// ---------------------------------------------------------------------------
template <int OUT>
__global__ __launch_bounds__(256) void gemm_bt(const unsigned short* __restrict__ A,
                                               const unsigned short* __restrict__ Bt,
                                               void* __restrict__ Cv) {
  __shared__ __align__(16) char smem[16384];    // A tile 8K | B tile 8K
  const int tid  = threadIdx.x;
  const int lane = tid & 63;
  const int w    = tid >> 6;
  const int bn = blockIdx.x, bm = blockIdx.y;
  const int wr = w >> 1, wc = w & 1;
  const int q16 = lane >> 4;
  const int l15 = lane & 15;

  f32x4 acc[4][4];
#pragma unroll
  for (int i = 0; i < 4; ++i)
#pragma unroll
    for (int j = 0; j < 4; ++j) acc[i][j] = (f32x4){0.f, 0.f, 0.f, 0.f};

  for (int k0 = 0; k0 < 2048; k0 += 32) {
    __syncthreads();
#pragma unroll
    for (int c = 0; c < 2; ++c) {
      int ch  = (w << 1) + c;
      int row = (ch << 4) + (lane >> 2);
      int colb = ((lane & 3) << 4) ^ (((row >> 1) & 3) << 4);
      const unsigned short* srcA = A + (size_t)((bm << 7) + row) * 2048 + k0 + (colb >> 1);
      llds16(srcA, smem + (ch << 10));
      const unsigned short* srcB = Bt + (size_t)((bn << 7) + row) * 2048 + k0 + (colb >> 1);
      llds16(srcB, smem + 8192 + (ch << 10));
    }
    asm volatile("s_waitcnt vmcnt(0)" ::: "memory");
    __syncthreads();

    bf16x8 af[4], bf[4];
#pragma unroll
    for (int mi = 0; mi < 4; ++mi) {
      int row = (wr << 6) + (mi << 4) + l15;
      af[mi] = *(const bf16x8*)(smem + (row << 6) + ((q16 << 4) ^ (((row >> 1) & 3) << 4)));
    }
#pragma unroll
    for (int ni = 0; ni < 4; ++ni) {
      int row = (wc << 6) + (ni << 4) + l15;
      bf[ni] = *(const bf16x8*)(smem + 8192 + (row << 6) + ((q16 << 4) ^ (((row >> 1) & 3) << 4)));
    }
#pragma unroll
    for (int mi = 0; mi < 4; ++mi)
#pragma unroll
      for (int ni = 0; ni < 4; ++ni)
        acc[mi][ni] = __builtin_amdgcn_mfma_f32_16x16x32_bf16(af[mi], bf[ni], acc[mi][ni], 0, 0, 0);
  }

  const int rb = q16 << 2;
#pragma unroll
  for (int mi = 0; mi < 4; ++mi) {
    int m0 = (bm << 7) + (wr << 6) + (mi << 4) + rb;
#pragma unroll
    for (int ni = 0; ni < 4; ++ni) {
      int n = (bn << 7) + (wc << 6) + (ni << 4) + l15;
      if constexpr (OUT == 0) {
        unsigned short* C = (unsigned short*)Cv;
#pragma unroll
        for (int j = 0; j < 4; ++j)
          C[(size_t)(m0 + j) * 2048 + n] = f2bf(acc[mi][ni][j]);
      } else if constexpr (OUT == 1) {
        u16x4 pk;
#pragma unroll
        for (int j = 0; j < 4; ++j) pk[j] = f2bf(acc[mi][ni][j]);
        int b = m0 >> 11, t = m0 & 2047;
        unsigned short* C = (unsigned short*)Cv;
        *(u16x4*)(C + ((size_t)((b << 4) + (n >> 7)) * 128 + (n & 127)) * 2048 + t) = pk;
      } else {
        float* C = (float*)Cv;
#pragma unroll
        for (int j = 0; j < 4; ++j)
          C[(size_t)(m0 + j) * 2048 + n] = acc[mi][ni][j];
      }
    }
  }
}

// ---------------------------------------------------------------------------
// V suffix sums at 32-row granularity.
// Suf[j][bh][d] = sum_{s >= 32j} V[b, s, h, d],  j in 0..64 (Suf[64] = 0).
// One wave per Vt row (= (bh,d)); lane l sums Vt[row][32l..32l+32), then a
// 64-lane inclusive suffix scan gives all 64 j values for that row.
// ---------------------------------------------------------------------------
__global__ __launch_bounds__(256) void vsuf_kernel(const unsigned short* __restrict__ Vt,
                                                   float* __restrict__ Suf) {
  const int row  = blockIdx.x * 4 + (threadIdx.x >> 6);  // 0..4095
  const int lane = threadIdx.x & 63;
  const unsigned short* vp = Vt + (size_t)row * 2048 + (lane << 5);
  float a = 0.f;
#pragma unroll
  for (int c = 0; c < 4; ++c) {
    bf16x8 v = *(const bf16x8*)(vp + (c << 3));
#pragma unroll
    for (int j = 0; j < 8; ++j) a += bf2f((unsigned short)v[j]);
  }
  float I = a;
#pragma unroll
  for (int off = 1; off < 64; off <<= 1) {
    float t = __shfl_down(I, off, 64);
    I += (lane + off < 64) ? t : 0.f;
  }
  Suf[(size_t)lane * 4096 + row] = I;
  if (lane == 0) Suf[(size_t)64 * 4096 + row] = 0.f;
}

// ---------------------------------------------------------------------------
// Fused attention, causal-skipped. Grid (16, 32). Block = 4 waves; each block
// processes TWO 64-row q-strips (i and 31-i) -> uniform 66 iterations/block.
// Wave w owns 16 q-rows of the strip. Per 32-s tile (2-phase pipelined,
// double-buffered LDS): QK^T (8 MFMA), p = exp(mask ? s*scale : 0), row-sum,
// P -> per-wave LDS -> A-frag, PV (8 MFMA). Tiles fully above the diagonal
// are replaced by the precomputed V-suffix sum (p == 1 exactly there).
// ---------------------------------------------------------------------------
__global__ __launch_bounds__(256) void attn_kernel(const unsigned short* __restrict__ Q,
                                                   const unsigned short* __restrict__ K,
                                                   const unsigned short* __restrict__ V,  // Vt layout
                                                   const float* __restrict__ Suf,
                                                   unsigned short* __restrict__ O) {
  __shared__ __align__(16) char smem[36864];  // K dbuf 2x8K | V dbuf 2x8K | P 4x1K
  const int tid  = threadIdx.x;
  const int lane = tid & 63;
  const int w    = tid >> 6;
  const int q16  = lane >> 4;
  const int l15  = lane & 15;
  const int bh = blockIdx.y;
  const int b  = bh >> 4;
  const float scale = 0.02209708691207961f;   // 1/sqrt(2048)
  const size_t qkbase = ((size_t)(b << 11)) * 2048 + ((size_t)(bh & 15) << 7);
  const size_t vbase  = (size_t)bh << 18;     // bh*128*2048
  const int rb = q16 << 2;
  char* Psm = smem + 32768 + (w << 10);

  auto stage = [&](int s0, int kb, int vb) {
#pragma unroll
    for (int c = 0; c < 2; ++c) {
      int ch = (w << 1) + c;
      int rowK = (ch << 2) + q16;                        // 4 rows / 1KB chunk
      int colbK = (l15 << 4) ^ ((rowK & 7) << 4);
      llds16(K + qkbase + (size_t)(s0 + rowK) * 2048 + (colbK >> 1), smem + kb + (ch << 10));
      int rowV = (ch << 4) + (lane >> 2);                // 16 rows / 1KB chunk
      int colbV = ((lane & 3) << 4) ^ (((rowV >> 2) & 3) << 4);
      llds16(V + vbase + (size_t)rowV * 2048 + s0 + (colbV >> 1), smem + vb + (ch << 10));
    }
  };

#pragma unroll 1
  for (int pi = 0; pi < 2; ++pi) {
    const int strip = pi ? (31 - blockIdx.x) : blockIdx.x;
    const int numIter = 2 * strip + 2;
    const int t0 = (strip << 6) + (w << 4);

    // Q fragments: lane holds Q[t0 + (lane&15)][8*(lane>>4) + j + 32*kk]
    bf16x8 qf[4];
    {
      const unsigned short* qp = Q + qkbase + (size_t)(t0 + l15) * 2048 + (q16 << 3);
#pragma unroll
      for (int kk = 0; kk < 4; ++kk) qf[kk] = *(const bf16x8*)(qp + (kk << 5));
    }

    f32x4 oacc[8];
#pragma unroll
    for (int i = 0; i < 8; ++i) oacc[i] = (f32x4){0.f, 0.f, 0.f, 0.f};
    float ell[4] = {0.f, 0.f, 0.f, 0.f};

    // prologue: stage tile 0 into buffer 0
    stage(0, 0, 16384);
    asm volatile("s_waitcnt vmcnt(0)" ::: "memory");
    __syncthreads();

    int cur = 0;
    for (int it = 0; it < numIter; ++it) {
      const int s0 = it << 5;
      if (it + 1 < numIter)
        stage(s0 + 32, (cur ^ 1) << 13, 16384 + ((cur ^ 1) << 13));

      if (s0 <= t0) {   // tile not entirely above this wave's diagonal
        const int kb = cur << 13;
        const int vb = 16384 + (cur << 13);

        // QK^T: two 16-col s-tiles
        f32x4 sA = (f32x4){0.f, 0.f, 0.f, 0.f}, sB = (f32x4){0.f, 0.f, 0.f, 0.f};
#pragma unroll
        for (int kk = 0; kk < 4; ++kk) {
          int r0 = l15;
          bf16x8 k0f = *(const bf16x8*)(smem + kb + (r0 << 8) + (((kk << 6) + (q16 << 4)) ^ ((r0 & 7) << 4)));
          sA = __builtin_amdgcn_mfma_f32_16x16x32_bf16(qf[kk], k0f, sA, 0, 0, 0);
          int r1 = 16 + l15;
          bf16x8 k1f = *(const bf16x8*)(smem + kb + (r1 << 8) + (((kk << 6) + (q16 << 4)) ^ ((r1 & 7) << 4)));
          sB = __builtin_amdgcn_mfma_f32_16x16x32_bf16(qf[kk], k1f, sB, 0, 0, 0);
        }

        // p = exp(masked*scale); masked (s>t) -> exp(0) = 1 (reference!)
        float pA[4], pB[4];
#pragma unroll
        for (int j = 0; j < 4; ++j) {
          int t  = t0 + rb + j;
          int sa = s0 + l15;
          float vA = (sa <= t)      ? sA[j] * scale : 0.f;
          float vB = (sa + 16 <= t) ? sB[j] * scale : 0.f;
          pA[j] = __expf(vA);
          pB[j] = __expf(vB);
          float r = pA[j] + pB[j];
          r += __shfl_xor(r, 1, 64);
          r += __shfl_xor(r, 2, 64);
          r += __shfl_xor(r, 4, 64);
          r += __shfl_xor(r, 8, 64);
          ell[j] += r;
        }

        // P -> per-wave LDS [16 t][32 s] bf16, swz: col ^= ((row>>1)&3)<<4
#pragma unroll
        for (int j = 0; j < 4; ++j) {
          int r   = rb + j;
          int swz = ((r >> 1) & 3) << 4;
          *(unsigned short*)(Psm + (r << 6) + ((l15 << 1) ^ swz))        = f2bf(pA[j]);
          *(unsigned short*)(Psm + (r << 6) + ((32 + (l15 << 1)) ^ swz)) = f2bf(pB[j]);
        }
        asm volatile("s_waitcnt lgkmcnt(0)" ::: "memory");

        bf16x8 pa;
        {
          int r = l15;
          pa = *(const bf16x8*)(Psm + (r << 6) + ((q16 << 4) ^ (((r >> 1) & 3) << 4)));
        }
#pragma unroll
        for (int ni = 0; ni < 8; ++ni) {
          int dr = (ni << 4) + l15;
          bf16x8 vbf = *(const bf16x8*)(smem + vb + (dr << 6) + ((q16 << 4) ^ (((dr >> 2) & 3) << 4)));
          oacc[ni] = __builtin_amdgcn_mfma_f32_16x16x32_bf16(pa, vbf, oacc[ni], 0, 0, 0);
        }
      }

      asm volatile("s_waitcnt vmcnt(0)" ::: "memory");
      __syncthreads();
      cur ^= 1;
    }

    // suffix correction: all s >= send have p == 1 exactly.
    const int send = (t0 & ~31) + 32;
    const float* sp = Suf + (size_t)(send >> 5) * 4096 + ((size_t)bh << 7);
    const float extra = (float)(2048 - send);
#pragma unroll
    for (int ni = 0; ni < 8; ++ni) {
      float sv = sp[(ni << 4) + l15];
#pragma unroll
      for (int j = 0; j < 4; ++j) oacc[ni][j] += sv;
    }

    // epilogue: O[t][h*128+d] = (oacc + suf) / (ell + extra)
#pragma unroll
    for (int j = 0; j < 4; ++j) {
      float inv = 1.0f / (ell[j] + extra);
      int t = t0 + rb + j;
      unsigned short* op = O + qkbase + (size_t)t * 2048;
#pragma unroll
      for (int ni = 0; ni < 8; ++ni)
        op[(ni << 4) + l15] = f2bf(oacc[ni][j] * inv);
    }
  }
}

// ---------------------------------------------------------------------------
// launch
// ---------------------------------------------------------------------------
extern "C" void kernel_launch(void* const* d_in, const int* in_sizes, int n_in,
                              void* d_out, int out_size, void* d_ws, size_t ws_size,
                              hipStream_t stream) {
  (void)in_sizes; (void)n_in; (void)out_size; (void)ws_size;
  const float* x  = (const float*)d_in[0];
  const float* Wq = (const float*)d_in[1];
  const float* Wk = (const float*)d_in[2];
  const float* Wv = (const float*)d_in[3];
  const float* Wo = (const float*)d_in[4];
  float* out = (float*)d_out;

  char* ws = (char*)d_ws;
  unsigned short* Xb  = (unsigned short*)(ws);                        // 16 MiB (reused as O)
  unsigned short* Wqt = (unsigned short*)(ws + 16777216);             // 8 MiB (reused as Suf)
  unsigned short* Wkt = (unsigned short*)(ws + 16777216 + 8388608);
  unsigned short* Wvt = (unsigned short*)(ws + 16777216 + 2 * 8388608);
  unsigned short* Wot = (unsigned short*)(ws + 16777216 + 3 * 8388608);
  unsigned short* Qb  = (unsigned short*)(ws + 50331648);             // 16 MiB
  unsigned short* Kb  = (unsigned short*)(ws + 67108864);             // 16 MiB
  unsigned short* Vt  = (unsigned short*)(ws + 83886080);             // 16 MiB
  unsigned short* Ob  = Xb;          // X dead after the V projection
  float*          Suf = (float*)Wqt; // Wq^T dead after the Q projection (1.06 MiB)

  cast_x_kernel<<<8192, 256, 0, stream>>>(x, Xb);
  {
    dim3 tb(32, 8), tg(64, 64);
    transpose_w_kernel<<<tg, tb, 0, stream>>>(Wq, Wqt);
    transpose_w_kernel<<<tg, tb, 0, stream>>>(Wk, Wkt);
    transpose_w_kernel<<<tg, tb, 0, stream>>>(Wv, Wvt);
    transpose_w_kernel<<<tg, tb, 0, stream>>>(Wo, Wot);
  }
  dim3 gg(16, 32);   // (N/128, M/128)
  gemm_bt<0><<<gg, 256, 0, stream>>>(Xb, Wqt, (void*)Qb);
  gemm_bt<0><<<gg, 256, 0, stream>>>(Xb, Wkt, (void*)Kb);
  gemm_bt<1><<<gg, 256, 0, stream>>>(Xb, Wvt, (void*)Vt);

  vsuf_kernel<<<1024, 256, 0, stream>>>(Vt, Suf);

  attn_kernel<<<dim3(16, 32), 256, 0, stream>>>(Qb, Kb, Vt, Suf, Ob);

  gemm_bt<2><<<gg, 256, 0, stream>>>(Ob, Wot, (void*)out);
}

// Round 3
// 305.835 us; speedup vs baseline: 1.2523x; 1.0790x over previous
//
#include <hip/hip_runtime.h>

// ---------------------------------------------------------------------------
// MultiHeadAttention forward, MI355X/gfx950.
// B=2, T=2048, D=2048, H=16, Dh=128. fp32 in/out, bf16 MFMA internally.
// Reference quirks (faithful): multiplicative tril mask (masked scores = 0,
// NOT -inf -> exp(0)=1 contributions over ALL 2048 cols), scale = 1/sqrt(T).
// Round 3: attn grid 1024 (one strip/block, LPT order), XCD-clustered bh
// decode (K/V L2-resident per XCD), deferred ell reduction; GEMM XCD swizzle.
// ---------------------------------------------------------------------------

typedef __attribute__((ext_vector_type(4))) float  f32x4;
typedef __attribute__((ext_vector_type(8))) short  bf16x8;
typedef __attribute__((ext_vector_type(4))) unsigned short u16x4;

#define AS1 __attribute__((address_space(1)))
#define AS3 __attribute__((address_space(3)))

__device__ __forceinline__ void llds16(const void* g, void* l) {
  __builtin_amdgcn_global_load_lds((const AS1 void*)g, (AS3 void*)l, 16, 0, 0);
}

__device__ __forceinline__ unsigned short f2bf(float f) {
  unsigned int u = __builtin_bit_cast(unsigned int, f);
  u += 0x7fffu + ((u >> 16) & 1u);   // RNE
  return (unsigned short)(u >> 16);
}

__device__ __forceinline__ float bf2f(unsigned short u) {
  return __builtin_bit_cast(float, (unsigned int)u << 16);
}

// ---------------------------------------------------------------------------
// cast x (fp32) -> bf16, 4 elements/thread
// ---------------------------------------------------------------------------
__global__ __launch_bounds__(256) void cast_x_kernel(const float* __restrict__ in,
                                                     unsigned short* __restrict__ out) {
  int i = blockIdx.x * 256 + threadIdx.x;
  f32x4 v = ((const f32x4*)in)[i];
  u16x4 o;
  o[0] = f2bf(v[0]); o[1] = f2bf(v[1]); o[2] = f2bf(v[2]); o[3] = f2bf(v[3]);
  ((u16x4*)out)[i] = o;
}

// ---------------------------------------------------------------------------
// W [2048][2048] fp32 -> Wt [n][k] bf16  (Wt[n][k] = W[k][n])
// ---------------------------------------------------------------------------
__global__ __launch_bounds__(256) void transpose_w_kernel(const float* __restrict__ W,
                                                          unsigned short* __restrict__ Wt) {
  __shared__ float tile[32][33];
  const int bx = blockIdx.x << 5;   // k base
  const int by = blockIdx.y << 5;   // n base
  const int tx = threadIdx.x;       // 0..31
  const int ty = threadIdx.y;       // 0..7
#pragma unroll
  for (int r = ty; r < 32; r += 8)
    tile[r][tx] = W[(size_t)(bx + r) * 2048 + by + tx];
  __syncthreads();
#pragma unroll
  for (int r = ty; r < 32; r += 8)
    Wt[(size_t)(by + r) * 2048 + bx + tx] = f2bf(tile[tx][r]);
}

// ---------------------------------------------------------------------------
// bf16 GEMM, C[M][N] = A[M][K] @ Bt[N][K]^T. M=4096, N=2048, K=2048.
// 128x128 tile, BK=32, 4 waves, 16x16x32 MFMA, both-sides XOR-swizzled LDS,
// global_load_lds width 16. Flat 512-block grid with XCD-clustered bn:
// each XCD owns 2 bn panels (1 MB B) -> B stays L2-resident for all 32 bm.
// OUT: 0 = bf16 row-major, 1 = bf16 scattered as Vt[(b*16+h)*128+d][t],
//      2 = fp32 row-major.
// ---------------------------------------------------------------------------
template <int OUT>
__global__ __launch_bounds__(256) void gemm_bt(const unsigned short* __restrict__ A,
                                               const unsigned short* __restrict__ Bt,
                                               void* __restrict__ Cv) {
  __shared__ __align__(16) char smem[16384];    // A tile 8K | B tile 8K
  const int tid  = threadIdx.x;
  const int lane = tid & 63;
  const int w    = tid >> 6;
  const int f    = blockIdx.x;
  const int bn   = ((f & 7) << 1) + ((f >> 3) & 1);   // 0..15, XCD-clustered
  const int bm   = f >> 4;                            // 0..31
  const int wr = w >> 1, wc = w & 1;
  const int q16 = lane >> 4;
  const int l15 = lane & 15;

  f32x4 acc[4][4];
#pragma unroll
  for (int i = 0; i < 4; ++i)
#pragma unroll
    for (int j = 0; j < 4; ++j) acc[i][j] = (f32x4){0.f, 0.f, 0.f, 0.f};

  for (int k0 = 0; k0 < 2048; k0 += 32) {
    __syncthreads();
#pragma unroll
    for (int c = 0; c < 2; ++c) {
      int ch  = (w << 1) + c;
      int row = (ch << 4) + (lane >> 2);
      int colb = ((lane & 3) << 4) ^ (((row >> 1) & 3) << 4);
      const unsigned short* srcA = A + (size_t)((bm << 7) + row) * 2048 + k0 + (colb >> 1);
      llds16(srcA, smem + (ch << 10));
      const unsigned short* srcB = Bt + (size_t)((bn << 7) + row) * 2048 + k0 + (colb >> 1);
      llds16(srcB, smem + 8192 + (ch << 10));
    }
    asm volatile("s_waitcnt vmcnt(0)" ::: "memory");
    __syncthreads();

    bf16x8 af[4], bf[4];
#pragma unroll
    for (int mi = 0; mi < 4; ++mi) {
      int row = (wr << 6) + (mi << 4) + l15;
      af[mi] = *(const bf16x8*)(smem + (row << 6) + ((q16 << 4) ^ (((row >> 1) & 3) << 4)));
    }
#pragma unroll
    for (int ni = 0; ni < 4; ++ni) {
      int row = (wc << 6) + (ni << 4) + l15;
      bf[ni] = *(const bf16x8*)(smem + 8192 + (row << 6) + ((q16 << 4) ^ (((row >> 1) & 3) << 4)));
    }
#pragma unroll
    for (int mi = 0; mi < 4; ++mi)
#pragma unroll
      for (int ni = 0; ni < 4; ++ni)
        acc[mi][ni] = __builtin_amdgcn_mfma_f32_16x16x32_bf16(af[mi], bf[ni], acc[mi][ni], 0, 0, 0);
  }

  const int rb = q16 << 2;
#pragma unroll
  for (int mi = 0; mi < 4; ++mi) {
    int m0 = (bm << 7) + (wr << 6) + (mi << 4) + rb;
#pragma unroll
    for (int ni = 0; ni < 4; ++ni) {
      int n = (bn << 7) + (wc << 6) + (ni << 4) + l15;
      if constexpr (OUT == 0) {
        unsigned short* C = (unsigned short*)Cv;
#pragma unroll
        for (int j = 0; j < 4; ++j)
          C[(size_t)(m0 + j) * 2048 + n] = f2bf(acc[mi][ni][j]);
      } else if constexpr (OUT == 1) {
        u16x4 pk;
#pragma unroll
        for (int j = 0; j < 4; ++j) pk[j] = f2bf(acc[mi][ni][j]);
        int b = m0 >> 11, t = m0 & 2047;
        unsigned short* C = (unsigned short*)Cv;
        *(u16x4*)(C + ((size_t)((b << 4) + (n >> 7)) * 128 + (n & 127)) * 2048 + t) = pk;
      } else {
        float* C = (float*)Cv;
#pragma unroll
        for (int j = 0; j < 4; ++j)
          C[(size_t)(m0 + j) * 2048 + n] = acc[mi][ni][j];
      }
    }
  }
}

// ---------------------------------------------------------------------------
// V suffix sums at 32-row granularity.
// Suf[j][bh][d] = sum_{s >= 32j} V[b, s, h, d],  j in 0..64 (Suf[64] = 0).
// ---------------------------------------------------------------------------
__global__ __launch_bounds__(256) void vsuf_kernel(const unsigned short* __restrict__ Vt,
                                                   float* __restrict__ Suf) {
  const int row  = blockIdx.x * 4 + (threadIdx.x >> 6);  // 0..4095
  const int lane = threadIdx.x & 63;
  const unsigned short* vp = Vt + (size_t)row * 2048 + (lane << 5);
  float a = 0.f;
#pragma unroll
  for (int c = 0; c < 4; ++c) {
    bf16x8 v = *(const bf16x8*)(vp + (c << 3));
#pragma unroll
    for (int j = 0; j < 8; ++j) a += bf2f((unsigned short)v[j]);
  }
  float I = a;
#pragma unroll
  for (int off = 1; off < 64; off <<= 1) {
    float t = __shfl_down(I, off, 64);
    I += (lane + off < 64) ? t : 0.f;
  }
  Suf[(size_t)lane * 4096 + row] = I;
  if (lane == 0) Suf[(size_t)64 * 4096 + row] = 0.f;
}

// ---------------------------------------------------------------------------
// Fused attention, causal-skipped. Flat grid 1024; decode:
//   xcd = f&7, bh = xcd*4 + ((f>>3)&3), strip = 31 - (f>>5)  (LPT order)
// -> each XCD serves exactly 4 bh (K+V working set 4 MB = one L2).
// Block = 4 waves, one 64-row q-strip; wave w owns 16 q-rows. Per 32-s tile
// (2-phase dbuf pipeline): QK^T (8 MFMA), p = exp(mask ? s*scale : 0),
// per-lane ell accumulate (reduction deferred to epilogue), P -> per-wave
// LDS -> A-frag, PV (8 MFMA). Tiles fully above the diagonal are covered by
// the precomputed V-suffix sums (p == 1 exactly there).
// ---------------------------------------------------------------------------
__global__ __launch_bounds__(256) void attn_kernel(const unsigned short* __restrict__ Q,
                                                   const unsigned short* __restrict__ K,
                                                   const unsigned short* __restrict__ V,  // Vt layout
                                                   const float* __restrict__ Suf,
                                                   unsigned short* __restrict__ O) {
  __shared__ __align__(16) char smem[36864];  // K dbuf 2x8K | V dbuf 2x8K | P 4x1K
  const int tid  = threadIdx.x;
  const int lane = tid & 63;
  const int w    = tid >> 6;
  const int q16  = lane >> 4;
  const int l15  = lane & 15;
  const int f    = blockIdx.x;
  const int bh    = ((f & 7) << 2) + ((f >> 3) & 3);
  const int strip = 31 - (f >> 5);
  const int b  = bh >> 4;
  const float scale = 0.02209708691207961f;   // 1/sqrt(2048)
  const size_t qkbase = ((size_t)(b << 11)) * 2048 + ((size_t)(bh & 15) << 7);
  const size_t vbase  = (size_t)bh << 18;     // bh*128*2048
  const int rb = q16 << 2;
  char* Psm = smem + 32768 + (w << 10);

  const int numIter = 2 * strip + 2;
  const int t0 = (strip << 6) + (w << 4);

  auto stage = [&](int s0, int kb, int vb) {
#pragma unroll
    for (int c = 0; c < 2; ++c) {
      int ch = (w << 1) + c;
      int rowK = (ch << 2) + q16;                        // 4 rows / 1KB chunk
      int colbK = (l15 << 4) ^ ((rowK & 7) << 4);
      llds16(K + qkbase + (size_t)(s0 + rowK) * 2048 + (colbK >> 1), smem + kb + (ch << 10));
      int rowV = (ch << 4) + (lane >> 2);                // 16 rows / 1KB chunk
      int colbV = ((lane & 3) << 4) ^ (((rowV >> 2) & 3) << 4);
      llds16(V + vbase + (size_t)rowV * 2048 + s0 + (colbV >> 1), smem + vb + (ch << 10));
    }
  };

  // Q fragments: lane holds Q[t0 + (lane&15)][8*(lane>>4) + j + 32*kk]
  bf16x8 qf[4];
  {
    const unsigned short* qp = Q + qkbase + (size_t)(t0 + l15) * 2048 + (q16 << 3);
#pragma unroll
    for (int kk = 0; kk < 4; ++kk) qf[kk] = *(const bf16x8*)(qp + (kk << 5));
  }

  f32x4 oacc[8];
#pragma unroll
  for (int i = 0; i < 8; ++i) oacc[i] = (f32x4){0.f, 0.f, 0.f, 0.f};
  float ell[4] = {0.f, 0.f, 0.f, 0.f};   // per-lane partial; reduced in epilogue

  // prologue: stage tile 0 into buffer 0
  stage(0, 0, 16384);
  asm volatile("s_waitcnt vmcnt(0)" ::: "memory");
  __syncthreads();

  int cur = 0;
  for (int it = 0; it < numIter; ++it) {
    const int s0 = it << 5;
    if (it + 1 < numIter)
      stage(s0 + 32, (cur ^ 1) << 13, 16384 + ((cur ^ 1) << 13));

    if (s0 <= t0) {   // tile not entirely above this wave's diagonal
      const int kb = cur << 13;
      const int vb = 16384 + (cur << 13);

      // QK^T: two 16-col s-tiles
      f32x4 sA = (f32x4){0.f, 0.f, 0.f, 0.f}, sB = (f32x4){0.f, 0.f, 0.f, 0.f};
#pragma unroll
      for (int kk = 0; kk < 4; ++kk) {
        int r0 = l15;
        bf16x8 k0f = *(const bf16x8*)(smem + kb + (r0 << 8) + (((kk << 6) + (q16 << 4)) ^ ((r0 & 7) << 4)));
        sA = __builtin_amdgcn_mfma_f32_16x16x32_bf16(qf[kk], k0f, sA, 0, 0, 0);
        int r1 = 16 + l15;
        bf16x8 k1f = *(const bf16x8*)(smem + kb + (r1 << 8) + (((kk << 6) + (q16 << 4)) ^ ((r1 & 7) << 4)));
        sB = __builtin_amdgcn_mfma_f32_16x16x32_bf16(qf[kk], k1f, sB, 0, 0, 0);
      }

      // p = exp(masked*scale); masked (s>t) -> exp(0) = 1 (reference!)
      float pA[4], pB[4];
#pragma unroll
      for (int j = 0; j < 4; ++j) {
        int t  = t0 + rb + j;
        int sa = s0 + l15;
        float vA = (sa <= t)      ? sA[j] * scale : 0.f;
        float vB = (sa + 16 <= t) ? sB[j] * scale : 0.f;
        pA[j] = __expf(vA);
        pB[j] = __expf(vB);
        ell[j] += pA[j] + pB[j];           // per-lane partial sum only
      }

      // P -> per-wave LDS [16 t][32 s] bf16, swz: col ^= ((row>>1)&3)<<4
#pragma unroll
      for (int j = 0; j < 4; ++j) {
        int r   = rb + j;
        int swz = ((r >> 1) & 3) << 4;
        *(unsigned short*)(Psm + (r << 6) + ((l15 << 1) ^ swz))        = f2bf(pA[j]);
        *(unsigned short*)(Psm + (r << 6) + ((32 + (l15 << 1)) ^ swz)) = f2bf(pB[j]);
      }
      asm volatile("s_waitcnt lgkmcnt(0)" ::: "memory");

      bf16x8 pa;
      {
        int r = l15;
        pa = *(const bf16x8*)(Psm + (r << 6) + ((q16 << 4) ^ (((r >> 1) & 3) << 4)));
      }
#pragma unroll
      for (int ni = 0; ni < 8; ++ni) {
        int dr = (ni << 4) + l15;
        bf16x8 vbf = *(const bf16x8*)(smem + vb + (dr << 6) + ((q16 << 4) ^ (((dr >> 2) & 3) << 4)));
        oacc[ni] = __builtin_amdgcn_mfma_f32_16x16x32_bf16(pa, vbf, oacc[ni], 0, 0, 0);
      }
    }

    asm volatile("s_waitcnt vmcnt(0)" ::: "memory");
    __syncthreads();
    cur ^= 1;
  }

  // suffix correction: all s >= send have p == 1 exactly.
  const int send = (t0 & ~31) + 32;
  const float* sp = Suf + (size_t)(send >> 5) * 4096 + ((size_t)bh << 7);
  const float extra = (float)(2048 - send);
#pragma unroll
  for (int ni = 0; ni < 8; ++ni) {
    float sv = sp[(ni << 4) + l15];
#pragma unroll
    for (int j = 0; j < 4; ++j) oacc[ni][j] += sv;
  }

  // deferred ell reduction (within each 16-lane row group), then normalize
#pragma unroll
  for (int j = 0; j < 4; ++j) {
    float r = ell[j];
    r += __shfl_xor(r, 1, 64);
    r += __shfl_xor(r, 2, 64);
    r += __shfl_xor(r, 4, 64);
    r += __shfl_xor(r, 8, 64);
    float inv = 1.0f / (r + extra);
    int t = t0 + rb + j;
    unsigned short* op = O + qkbase + (size_t)t * 2048;
#pragma unroll
    for (int ni = 0; ni < 8; ++ni)
      op[(ni << 4) + l15] = f2bf(oacc[ni][j] * inv);
  }
}

// ---------------------------------------------------------------------------
// launch
// ---------------------------------------------------------------------------
extern "C" void kernel_launch(void* const* d_in, const int* in_sizes, int n_in,
                              void* d_out, int out_size, void* d_ws, size_t ws_size,
                              hipStream_t stream) {
  (void)in_sizes; (void)n_in; (void)out_size; (void)ws_size;
  const float* x  = (const float*)d_in[0];
  const float* Wq = (const float*)d_in[1];
  const float* Wk = (const float*)d_in[2];
  const float* Wv = (const float*)d_in[3];
  const float* Wo = (const float*)d_in[4];
  float* out = (float*)d_out;

  char* ws = (char*)d_ws;
  unsigned short* Xb  = (unsigned short*)(ws);                        // 16 MiB (reused as O)
  unsigned short* Wqt = (unsigned short*)(ws + 16777216);             // 8 MiB (reused as Suf)
  unsigned short* Wkt = (unsigned short*)(ws + 16777216 + 8388608);
  unsigned short* Wvt = (unsigned short*)(ws + 16777216 + 2 * 8388608);
  unsigned short* Wot = (unsigned short*)(ws + 16777216 + 3 * 8388608);
  unsigned short* Qb  = (unsigned short*)(ws + 50331648);             // 16 MiB
  unsigned short* Kb  = (unsigned short*)(ws + 67108864);             // 16 MiB
  unsigned short* Vt  = (unsigned short*)(ws + 83886080);             // 16 MiB
  unsigned short* Ob  = Xb;          // X dead after the V projection
  float*          Suf = (float*)Wqt; // Wq^T dead after the Q projection (1.06 MiB)

  cast_x_kernel<<<8192, 256, 0, stream>>>(x, Xb);
  {
    dim3 tb(32, 8), tg(64, 64);
    transpose_w_kernel<<<tg, tb, 0, stream>>>(Wq, Wqt);
    transpose_w_kernel<<<tg, tb, 0, stream>>>(Wk, Wkt);
    transpose_w_kernel<<<tg, tb, 0, stream>>>(Wv, Wvt);
    transpose_w_kernel<<<tg, tb, 0, stream>>>(Wo, Wot);
  }
  gemm_bt<0><<<512, 256, 0, stream>>>(Xb, Wqt, (void*)Qb);
  gemm_bt<0><<<512, 256, 0, stream>>>(Xb, Wkt, (void*)Kb);
  gemm_bt<1><<<512, 256, 0, stream>>>(Xb, Wvt, (void*)Vt);

  vsuf_kernel<<<1024, 256, 0, stream>>>(Vt, Suf);

  attn_kernel<<<1024, 256, 0, stream>>>(Qb, Kb, Vt, Suf, Ob);

  gemm_bt<2><<<512, 256, 0, stream>>>(Ob, Wot, (void*)out);
}

// Round 4
// 273.420 us; speedup vs baseline: 1.4007x; 1.1186x over previous
//
#include <hip/hip_runtime.h>

// ---------------------------------------------------------------------------
// MultiHeadAttention forward, MI355X/gfx950.
// B=2, T=2048, D=2048, H=16, Dh=128. fp32 in/out, bf16 MFMA internally.
// Reference quirks (faithful): multiplicative tril mask (masked scores = 0,
// NOT -inf -> exp(0)=1 contributions over ALL 2048 cols), scale = 1/sqrt(T).
// Round 4: GEMMs -> deep-pipelined ring-4 counted-vmcnt schedule (T3+T4+T5),
// 128x256 tile, 8 waves, 96 KiB LDS, grid 256 (1 block/CU), XCD-clustered.
// Attn unchanged from round 3.
// ---------------------------------------------------------------------------

typedef __attribute__((ext_vector_type(4))) float  f32x4;
typedef __attribute__((ext_vector_type(8))) short  bf16x8;
typedef __attribute__((ext_vector_type(4))) unsigned short u16x4;

#define AS1 __attribute__((address_space(1)))
#define AS3 __attribute__((address_space(3)))

__device__ __forceinline__ void llds16(const void* g, void* l) {
  __builtin_amdgcn_global_load_lds((const AS1 void*)g, (AS3 void*)l, 16, 0, 0);
}

__device__ __forceinline__ unsigned short f2bf(float f) {
  unsigned int u = __builtin_bit_cast(unsigned int, f);
  u += 0x7fffu + ((u >> 16) & 1u);   // RNE
  return (unsigned short)(u >> 16);
}

__device__ __forceinline__ float bf2f(unsigned short u) {
  return __builtin_bit_cast(float, (unsigned int)u << 16);
}

// ---------------------------------------------------------------------------
// cast x (fp32) -> bf16, 4 elements/thread
// ---------------------------------------------------------------------------
__global__ __launch_bounds__(256) void cast_x_kernel(const float* __restrict__ in,
                                                     unsigned short* __restrict__ out) {
  int i = blockIdx.x * 256 + threadIdx.x;
  f32x4 v = ((const f32x4*)in)[i];
  u16x4 o;
  o[0] = f2bf(v[0]); o[1] = f2bf(v[1]); o[2] = f2bf(v[2]); o[3] = f2bf(v[3]);
  ((u16x4*)out)[i] = o;
}

// ---------------------------------------------------------------------------
// W [2048][2048] fp32 -> Wt [n][k] bf16  (Wt[n][k] = W[k][n])
// ---------------------------------------------------------------------------
__global__ __launch_bounds__(256) void transpose_w_kernel(const float* __restrict__ W,
                                                          unsigned short* __restrict__ Wt) {
  __shared__ float tile[32][33];
  const int bx = blockIdx.x << 5;   // k base
  const int by = blockIdx.y << 5;   // n base
  const int tx = threadIdx.x;       // 0..31
  const int ty = threadIdx.y;       // 0..7
#pragma unroll
  for (int r = ty; r < 32; r += 8)
    tile[r][tx] = W[(size_t)(bx + r) * 2048 + by + tx];
  __syncthreads();
#pragma unroll
  for (int r = ty; r < 32; r += 8)
    Wt[(size_t)(by + r) * 2048 + bx + tx] = f2bf(tile[tx][r]);
}

// ---------------------------------------------------------------------------
// bf16 GEMM, C[M][N] = A[M][K] @ Bt[N][K]^T. M=4096, N=2048, K=2048.
// Deep-pipelined: 128x256 tile, BK=32, 8 waves (2Mx4N, 64x64 each), ring of
// 4 LDS slots (24 KiB = A 8K + B 16K), prefetch depth 3, counted vmcnt(9)
// (never 0 in main loop), raw s_barrier (no __syncthreads drain), setprio
// around the MFMA cluster. LDS XOR-swizzled both sides (2-way max).
// Grid 256 flat, XCD-clustered 8bm x 4bn per XCD.
// OUT: 0 = bf16 row-major, 1 = bf16 scattered as Vt[(b*16+h)*128+d][t],
//      2 = fp32 row-major.
// ---------------------------------------------------------------------------
template <int OUT>
__global__ __launch_bounds__(512, 2) void gemm_bt(const unsigned short* __restrict__ A,
                                                  const unsigned short* __restrict__ Bt,
                                                  void* __restrict__ Cv) {
  __shared__ __align__(16) char smem[98304];   // 4 slots x 24576 B
  const int tid  = threadIdx.x;
  const int lane = tid & 63;
  const int w    = tid >> 6;                   // 0..7
  const int f    = blockIdx.x;
  const int xcd  = f & 7;
  const int g    = f >> 3;                     // 0..31
  const int bm   = ((xcd >> 1) << 3) + (g & 7);   // 0..31 (128-row tiles)
  const int bn   = ((xcd & 1) << 2) + (g >> 3);   // 0..7  (256-col tiles)
  const int wr = w >> 2, wc = w & 3;
  const int q16 = lane >> 4;
  const int l15 = lane & 15;

  // staging source addresses (pre-swizzled; LDS dest is linear).
  // chunk idx (A): w*64+lane -> row = idx>>2 in [0,128), phys col-chunk = idx&3
  // logical chunk = phys ^ ((row>>1)&3); each chunk = 8 bf16.
  const int aIdx = (w << 6) + lane;
  const int aRow = aIdx >> 2, aCph = aIdx & 3;
  const unsigned short* aSrc = A + (size_t)((bm << 7) + aRow) * 2048
                                 + ((aCph ^ ((aRow >> 1) & 3)) << 3);
  const int bRow0 = aIdx >> 2, bCph0 = aIdx & 3;          // B rows 0..127
  const int bIdx1 = 512 + aIdx;
  const int bRow1 = bIdx1 >> 2, bCph1 = bIdx1 & 3;        // B rows 128..255
  const unsigned short* bSrc0 = Bt + (size_t)((bn << 8) + bRow0) * 2048
                                  + ((bCph0 ^ ((bRow0 >> 1) & 3)) << 3);
  const unsigned short* bSrc1 = Bt + (size_t)((bn << 8) + bRow1) * 2048
                                  + ((bCph1 ^ ((bRow1 >> 1) & 3)) << 3);

  // ds_read lane offsets (slot-relative). row = base16 + l15 with base16 %16==0
  // -> swz = (l15>>1)&3 for every fragment.
  const int swx = ((q16 ^ ((l15 >> 1) & 3)) << 4);
  const int aoff = ((wr << 6) + l15) * 64 + swx;           // + mi*1024
  const int boff = 8192 + ((wc << 6) + l15) * 64 + swx;    // + ni*1024

  f32x4 acc[4][4];
#pragma unroll
  for (int i = 0; i < 4; ++i)
#pragma unroll
    for (int j = 0; j < 4; ++j) acc[i][j] = (f32x4){0.f, 0.f, 0.f, 0.f};

  auto stageT = [&](int t, int slot) {
    char* sb = smem + slot * 24576 + (w << 10);
    const size_t ko = (size_t)t << 5;        // k element offset = t*32
    llds16(aSrc + ko, sb);
    llds16(bSrc0 + ko, sb + 8192);
    llds16(bSrc1 + ko, sb + 16384);
  };

  auto computeT = [&](int slot) {
    const char* base = smem + slot * 24576;
    bf16x8 af[4], bf[4];
#pragma unroll
    for (int mi = 0; mi < 4; ++mi) af[mi] = *(const bf16x8*)(base + aoff + (mi << 10));
#pragma unroll
    for (int ni = 0; ni < 4; ++ni) bf[ni] = *(const bf16x8*)(base + boff + (ni << 10));
    __builtin_amdgcn_s_setprio(1);
#pragma unroll
    for (int mi = 0; mi < 4; ++mi)
#pragma unroll
      for (int ni = 0; ni < 4; ++ni)
        acc[mi][ni] = __builtin_amdgcn_mfma_f32_16x16x32_bf16(af[mi], bf[ni], acc[mi][ni], 0, 0, 0);
    __builtin_amdgcn_s_setprio(0);
  };

  // prologue: tiles 0,1,2 in flight (9 loads)
  stageT(0, 0); stageT(1, 1); stageT(2, 2);

  // main loop: tiles 0..59, staging 3..62; 3 tiles (9 loads) stay in flight.
#pragma unroll 1
  for (int i = 0; i < 60; i += 4) {
#pragma unroll
    for (int u = 0; u < 4; ++u) {
      stageT(i + u + 3, (u + 3) & 3);
      asm volatile("s_waitcnt vmcnt(9)" ::: "memory");   // tile i+u landed (own wave)
      __builtin_amdgcn_s_barrier();                      // all waves landed
      computeT(u);
      __builtin_amdgcn_s_barrier();                      // slot free for restage
    }
  }
  // tail: tiles 60..63 (stage 63, then exact-count drains 9/6/3/0)
  stageT(63, 3);
  asm volatile("s_waitcnt vmcnt(9)" ::: "memory");
  __builtin_amdgcn_s_barrier();
  computeT(0);
  __builtin_amdgcn_s_barrier();
  asm volatile("s_waitcnt vmcnt(6)" ::: "memory");
  __builtin_amdgcn_s_barrier();
  computeT(1);
  __builtin_amdgcn_s_barrier();
  asm volatile("s_waitcnt vmcnt(3)" ::: "memory");
  __builtin_amdgcn_s_barrier();
  computeT(2);
  __builtin_amdgcn_s_barrier();
  asm volatile("s_waitcnt vmcnt(0)" ::: "memory");
  __builtin_amdgcn_s_barrier();
  computeT(3);

  // epilogue. C/D layout: col = lane&15, row = (lane>>4)*4 + reg  [m89]
  const int rb = q16 << 2;
#pragma unroll
  for (int mi = 0; mi < 4; ++mi) {
    int m0 = (bm << 7) + (wr << 6) + (mi << 4) + rb;
#pragma unroll
    for (int ni = 0; ni < 4; ++ni) {
      int n = (bn << 8) + (wc << 6) + (ni << 4) + l15;
      if constexpr (OUT == 0) {
        unsigned short* C = (unsigned short*)Cv;
#pragma unroll
        for (int j = 0; j < 4; ++j)
          C[(size_t)(m0 + j) * 2048 + n] = f2bf(acc[mi][ni][j]);
      } else if constexpr (OUT == 1) {
        u16x4 pk;
#pragma unroll
        for (int j = 0; j < 4; ++j) pk[j] = f2bf(acc[mi][ni][j]);
        int b = m0 >> 11, t = m0 & 2047;
        unsigned short* C = (unsigned short*)Cv;
        *(u16x4*)(C + ((size_t)((b << 4) + (n >> 7)) * 128 + (n & 127)) * 2048 + t) = pk;
      } else {
        float* C = (float*)Cv;
#pragma unroll
        for (int j = 0; j < 4; ++j)
          C[(size_t)(m0 + j) * 2048 + n] = acc[mi][ni][j];
      }
    }
  }
}

// ---------------------------------------------------------------------------
// V suffix sums at 32-row granularity.
// Suf[j][bh][d] = sum_{s >= 32j} V[b, s, h, d],  j in 0..64 (Suf[64] = 0).
// ---------------------------------------------------------------------------
__global__ __launch_bounds__(256) void vsuf_kernel(const unsigned short* __restrict__ Vt,
                                                   float* __restrict__ Suf) {
  const int row  = blockIdx.x * 4 + (threadIdx.x >> 6);  // 0..4095
  const int lane = threadIdx.x & 63;
  const unsigned short* vp = Vt + (size_t)row * 2048 + (lane << 5);
  float a = 0.f;
#pragma unroll
  for (int c = 0; c < 4; ++c) {
    bf16x8 v = *(const bf16x8*)(vp + (c << 3));
#pragma unroll
    for (int j = 0; j < 8; ++j) a += bf2f((unsigned short)v[j]);
  }
  float I = a;
#pragma unroll
  for (int off = 1; off < 64; off <<= 1) {
    float t = __shfl_down(I, off, 64);
    I += (lane + off < 64) ? t : 0.f;
  }
  Suf[(size_t)lane * 4096 + row] = I;
  if (lane == 0) Suf[(size_t)64 * 4096 + row] = 0.f;
}

// ---------------------------------------------------------------------------
// Fused attention, causal-skipped. Flat grid 1024; decode:
//   xcd = f&7, bh = xcd*4 + ((f>>3)&3), strip = 31 - (f>>5)  (LPT order)
// -> each XCD serves exactly 4 bh (K+V working set 4 MB = one L2).
// Block = 4 waves, one 64-row q-strip; wave w owns 16 q-rows. Per 32-s tile
// (2-phase dbuf pipeline): QK^T (8 MFMA), p = exp(mask ? s*scale : 0),
// per-lane ell accumulate (reduction deferred to epilogue), P -> per-wave
// LDS -> A-frag, PV (8 MFMA). Tiles fully above the diagonal are covered by
// the precomputed V-suffix sums (p == 1 exactly there).
// ---------------------------------------------------------------------------
__global__ __launch_bounds__(256) void attn_kernel(const unsigned short* __restrict__ Q,
                                                   const unsigned short* __restrict__ K,
                                                   const unsigned short* __restrict__ V,  // Vt layout
                                                   const float* __restrict__ Suf,
                                                   unsigned short* __restrict__ O) {
  __shared__ __align__(16) char smem[36864];  // K dbuf 2x8K | V dbuf 2x8K | P 4x1K
  const int tid  = threadIdx.x;
  const int lane = tid & 63;
  const int w    = tid >> 6;
  const int q16  = lane >> 4;
  const int l15  = lane & 15;
  const int f    = blockIdx.x;
  const int bh    = ((f & 7) << 2) + ((f >> 3) & 3);
  const int strip = 31 - (f >> 5);
  const int b  = bh >> 4;
  const float scale = 0.02209708691207961f;   // 1/sqrt(2048)
  const size_t qkbase = ((size_t)(b << 11)) * 2048 + ((size_t)(bh & 15) << 7);
  const size_t vbase  = (size_t)bh << 18;     // bh*128*2048
  const int rb = q16 << 2;
  char* Psm = smem + 32768 + (w << 10);

  const int numIter = 2 * strip + 2;
  const int t0 = (strip << 6) + (w << 4);

  auto stage = [&](int s0, int kb, int vb) {
#pragma unroll
    for (int c = 0; c < 2; ++c) {
      int ch = (w << 1) + c;
      int rowK = (ch << 2) + q16;                        // 4 rows / 1KB chunk
      int colbK = (l15 << 4) ^ ((rowK & 7) << 4);
      llds16(K + qkbase + (size_t)(s0 + rowK) * 2048 + (colbK >> 1), smem + kb + (ch << 10));
      int rowV = (ch << 4) + (lane >> 2);                // 16 rows / 1KB chunk
      int colbV = ((lane & 3) << 4) ^ (((rowV >> 2) & 3) << 4);
      llds16(V + vbase + (size_t)rowV * 2048 + s0 + (colbV >> 1), smem + vb + (ch << 10));
    }
  };

  // Q fragments: lane holds Q[t0 + (lane&15)][8*(lane>>4) + j + 32*kk]
  bf16x8 qf[4];
  {
    const unsigned short* qp = Q + qkbase + (size_t)(t0 + l15) * 2048 + (q16 << 3);
#pragma unroll
    for (int kk = 0; kk < 4; ++kk) qf[kk] = *(const bf16x8*)(qp + (kk << 5));
  }

  f32x4 oacc[8];
#pragma unroll
  for (int i = 0; i < 8; ++i) oacc[i] = (f32x4){0.f, 0.f, 0.f, 0.f};
  float ell[4] = {0.f, 0.f, 0.f, 0.f};   // per-lane partial; reduced in epilogue

  // prologue: stage tile 0 into buffer 0
  stage(0, 0, 16384);
  asm volatile("s_waitcnt vmcnt(0)" ::: "memory");
  __syncthreads();

  int cur = 0;
  for (int it = 0; it < numIter; ++it) {
    const int s0 = it << 5;
    if (it + 1 < numIter)
      stage(s0 + 32, (cur ^ 1) << 13, 16384 + ((cur ^ 1) << 13));

    if (s0 <= t0) {   // tile not entirely above this wave's diagonal
      const int kb = cur << 13;
      const int vb = 16384 + (cur << 13);

      // QK^T: two 16-col s-tiles
      f32x4 sA = (f32x4){0.f, 0.f, 0.f, 0.f}, sB = (f32x4){0.f, 0.f, 0.f, 0.f};
#pragma unroll
      for (int kk = 0; kk < 4; ++kk) {
        int r0 = l15;
        bf16x8 k0f = *(const bf16x8*)(smem + kb + (r0 << 8) + (((kk << 6) + (q16 << 4)) ^ ((r0 & 7) << 4)));
        sA = __builtin_amdgcn_mfma_f32_16x16x32_bf16(qf[kk], k0f, sA, 0, 0, 0);
        int r1 = 16 + l15;
        bf16x8 k1f = *(const bf16x8*)(smem + kb + (r1 << 8) + (((kk << 6) + (q16 << 4)) ^ ((r1 & 7) << 4)));
        sB = __builtin_amdgcn_mfma_f32_16x16x32_bf16(qf[kk], k1f, sB, 0, 0, 0);
      }

      // p = exp(masked*scale); masked (s>t) -> exp(0) = 1 (reference!)
      float pA[4], pB[4];
#pragma unroll
      for (int j = 0; j < 4; ++j) {
        int t  = t0 + rb + j;
        int sa = s0 + l15;
        float vA = (sa <= t)      ? sA[j] * scale : 0.f;
        float vB = (sa + 16 <= t) ? sB[j] * scale : 0.f;
        pA[j] = __expf(vA);
        pB[j] = __expf(vB);
        ell[j] += pA[j] + pB[j];           // per-lane partial sum only
      }

      // P -> per-wave LDS [16 t][32 s] bf16, swz: col ^= ((row>>1)&3)<<4
#pragma unroll
      for (int j = 0; j < 4; ++j) {
        int r   = rb + j;
        int swz = ((r >> 1) & 3) << 4;
        *(unsigned short*)(Psm + (r << 6) + ((l15 << 1) ^ swz))        = f2bf(pA[j]);
        *(unsigned short*)(Psm + (r << 6) + ((32 + (l15 << 1)) ^ swz)) = f2bf(pB[j]);
      }
      asm volatile("s_waitcnt lgkmcnt(0)" ::: "memory");

      bf16x8 pa;
      {
        int r = l15;
        pa = *(const bf16x8*)(Psm + (r << 6) + ((q16 << 4) ^ (((r >> 1) & 3) << 4)));
      }
#pragma unroll
      for (int ni = 0; ni < 8; ++ni) {
        int dr = (ni << 4) + l15;
        bf16x8 vbf = *(const bf16x8*)(smem + vb + (dr << 6) + ((q16 << 4) ^ (((dr >> 2) & 3) << 4)));
        oacc[ni] = __builtin_amdgcn_mfma_f32_16x16x32_bf16(pa, vbf, oacc[ni], 0, 0, 0);
      }
    }

    asm volatile("s_waitcnt vmcnt(0)" ::: "memory");
    __syncthreads();
    cur ^= 1;
  }

  // suffix correction: all s >= send have p == 1 exactly.
  const int send = (t0 & ~31) + 32;
  const float* sp = Suf + (size_t)(send >> 5) * 4096 + ((size_t)bh << 7);
  const float extra = (float)(2048 - send);
#pragma unroll
  for (int ni = 0; ni < 8; ++ni) {
    float sv = sp[(ni << 4) + l15];
#pragma unroll
    for (int j = 0; j < 4; ++j) oacc[ni][j] += sv;
  }

  // deferred ell reduction (within each 16-lane row group), then normalize
#pragma unroll
  for (int j = 0; j < 4; ++j) {
    float r = ell[j];
    r += __shfl_xor(r, 1, 64);
    r += __shfl_xor(r, 2, 64);
    r += __shfl_xor(r, 4, 64);
    r += __shfl_xor(r, 8, 64);
    float inv = 1.0f / (r + extra);
    int t = t0 + rb + j;
    unsigned short* op = O + qkbase + (size_t)t * 2048;
#pragma unroll
    for (int ni = 0; ni < 8; ++ni)
      op[(ni << 4) + l15] = f2bf(oacc[ni][j] * inv);
  }
}

// ---------------------------------------------------------------------------
// launch
// ---------------------------------------------------------------------------
extern "C" void kernel_launch(void* const* d_in, const int* in_sizes, int n_in,
                              void* d_out, int out_size, void* d_ws, size_t ws_size,
                              hipStream_t stream) {
  (void)in_sizes; (void)n_in; (void)out_size; (void)ws_size;
  const float* x  = (const float*)d_in[0];
  const float* Wq = (const float*)d_in[1];
  const float* Wk = (const float*)d_in[2];
  const float* Wv = (const float*)d_in[3];
  const float* Wo = (const float*)d_in[4];
  float* out = (float*)d_out;

  char* ws = (char*)d_ws;
  unsigned short* Xb  = (unsigned short*)(ws);                        // 16 MiB (reused as O)
  unsigned short* Wqt = (unsigned short*)(ws + 16777216);             // 8 MiB (reused as Suf)
  unsigned short* Wkt = (unsigned short*)(ws + 16777216 + 8388608);
  unsigned short* Wvt = (unsigned short*)(ws + 16777216 + 2 * 8388608);
  unsigned short* Wot = (unsigned short*)(ws + 16777216 + 3 * 8388608);
  unsigned short* Qb  = (unsigned short*)(ws + 50331648);             // 16 MiB
  unsigned short* Kb  = (unsigned short*)(ws + 67108864);             // 16 MiB
  unsigned short* Vt  = (unsigned short*)(ws + 83886080);             // 16 MiB
  unsigned short* Ob  = Xb;          // X dead after the V projection
  float*          Suf = (float*)Wqt; // Wq^T dead after the Q projection (1.06 MiB)

  cast_x_kernel<<<8192, 256, 0, stream>>>(x, Xb);
  {
    dim3 tb(32, 8), tg(64, 64);
    transpose_w_kernel<<<tg, tb, 0, stream>>>(Wq, Wqt);
    transpose_w_kernel<<<tg, tb, 0, stream>>>(Wk, Wkt);
    transpose_w_kernel<<<tg, tb, 0, stream>>>(Wv, Wvt);
    transpose_w_kernel<<<tg, tb, 0, stream>>>(Wo, Wot);
  }
  gemm_bt<0><<<256, 512, 0, stream>>>(Xb, Wqt, (void*)Qb);
  gemm_bt<0><<<256, 512, 0, stream>>>(Xb, Wkt, (void*)Kb);
  gemm_bt<1><<<256, 512, 0, stream>>>(Xb, Wvt, (void*)Vt);

  vsuf_kernel<<<1024, 256, 0, stream>>>(Vt, Suf);

  attn_kernel<<<1024, 256, 0, stream>>>(Qb, Kb, Vt, Suf, Ob);

  gemm_bt<2><<<256, 512, 0, stream>>>(Ob, Wot, (void*)out);
}

// Round 5
// 265.632 us; speedup vs baseline: 1.4418x; 1.0293x over previous
//
#include <hip/hip_runtime.h>

// ---------------------------------------------------------------------------
// MultiHeadAttention forward, MI355X/gfx950.
// B=2, T=2048, D=2048, H=16, Dh=128. fp32 in/out, bf16 MFMA internally.
// Reference quirks (faithful): multiplicative tril mask (masked scores = 0,
// NOT -inf -> exp(0)=1 contributions over ALL 2048 cols), scale = 1/sqrt(T).
// Round 5: GEMM -> register-prefetch pipeline (1 barrier/K-step, ds_read of
// step u+1 overlapped with MFMA of step u, counted vmcnt(3)); Q/K/V fused
// into one GEMM (N=6144) with 1/sqrt(T) folded into the Q epilogue; attn
// mask-branch only on the straddling tile + cheaper P pack.
// ---------------------------------------------------------------------------

typedef __attribute__((ext_vector_type(4))) float  f32x4;
typedef __attribute__((ext_vector_type(8))) short  bf16x8;
typedef __attribute__((ext_vector_type(4))) unsigned short u16x4;

#define AS1 __attribute__((address_space(1)))
#define AS3 __attribute__((address_space(3)))

__device__ __forceinline__ void llds16(const void* g, void* l) {
  __builtin_amdgcn_global_load_lds((const AS1 void*)g, (AS3 void*)l, 16, 0, 0);
}

__device__ __forceinline__ unsigned short f2bf(float f) {   // RNE
  unsigned int u = __builtin_bit_cast(unsigned int, f);
  u += 0x7fffu + ((u >> 16) & 1u);
  return (unsigned short)(u >> 16);
}

__device__ __forceinline__ unsigned short f2bfru(float f) { // round-half-up (2 insts)
  return (unsigned short)((__builtin_bit_cast(unsigned int, f) + 0x8000u) >> 16);
}

__device__ __forceinline__ float bf2f(unsigned short u) {
  return __builtin_bit_cast(float, (unsigned int)u << 16);
}

// ---------------------------------------------------------------------------
// cast x (fp32) -> bf16, 4 elements/thread
// ---------------------------------------------------------------------------
__global__ __launch_bounds__(256) void cast_x_kernel(const float* __restrict__ in,
                                                     unsigned short* __restrict__ out) {
  int i = blockIdx.x * 256 + threadIdx.x;
  f32x4 v = ((const f32x4*)in)[i];
  u16x4 o;
  o[0] = f2bf(v[0]); o[1] = f2bf(v[1]); o[2] = f2bf(v[2]); o[3] = f2bf(v[3]);
  ((u16x4*)out)[i] = o;
}

// ---------------------------------------------------------------------------
// 4 weight transposes in one launch. W [2048][2048] fp32 -> Wt[n][k] bf16.
// ---------------------------------------------------------------------------
__global__ __launch_bounds__(256) void transpose_w4_kernel(
    const float* __restrict__ W0, const float* __restrict__ W1,
    const float* __restrict__ W2, const float* __restrict__ W3,
    unsigned short* __restrict__ T0, unsigned short* __restrict__ T1,
    unsigned short* __restrict__ T2, unsigned short* __restrict__ T3) {
  __shared__ float tile[32][33];
  const int z = blockIdx.z;
  const float* W = (z == 0) ? W0 : (z == 1) ? W1 : (z == 2) ? W2 : W3;
  unsigned short* Wt = (z == 0) ? T0 : (z == 1) ? T1 : (z == 2) ? T2 : T3;
  const int bx = blockIdx.x << 5;   // k base
  const int by = blockIdx.y << 5;   // n base
  const int tx = threadIdx.x;       // 0..31
  const int ty = threadIdx.y;       // 0..7
#pragma unroll
  for (int r = ty; r < 32; r += 8)
    tile[r][tx] = W[(size_t)(bx + r) * 2048 + by + tx];
  __syncthreads();
#pragma unroll
  for (int r = ty; r < 32; r += 8)
    Wt[(size_t)(by + r) * 2048 + bx + tx] = f2bf(tile[tx][r]);
}

// ---------------------------------------------------------------------------
// bf16 GEMM, C[M][N] = A[M][K] @ Bt[N][K]^T, K=2048, M=4096.
// Register-prefetch pipeline: 128x256 tile, BK=32, 8 waves (2Mx4N, 64x64),
// ring of 4 LDS slots (24 KiB each), ONE barrier per K-step, counted
// vmcnt(3) (drains only in the tail), ds_read of step u+1 overlapped with
// MFMA of step u. LDS XOR-swizzled both sides. setprio around MFMA cluster.
// EPI 0: fused QKV (N=6144, grid 768, 3 bn/XCD). Q region scaled by 1/sqrt(T).
// EPI 1: fp32 out (N=2048, grid 256, 1 bn/XCD).
// ---------------------------------------------------------------------------
template <int EPI>
__global__ __launch_bounds__(512, 2) void gemm_pipe(const unsigned short* __restrict__ A,
                                                    const unsigned short* __restrict__ Bt,
                                                    unsigned short* __restrict__ Qb,
                                                    unsigned short* __restrict__ Kb,
                                                    unsigned short* __restrict__ Vt,
                                                    float* __restrict__ Co) {
  __shared__ __align__(16) char smem[98304];   // 4 slots x 24576 B
  const int tid  = threadIdx.x;
  const int lane = tid & 63;
  const int w    = tid >> 6;                   // 0..7
  const int f    = blockIdx.x;
  const int xcd  = f & 7;
  const int g    = f >> 3;
  int bm, bn;
  if constexpr (EPI == 0) { bn = xcd * 3 + (g % 3); bm = g / 3; }  // 24 x 32
  else                    { bn = xcd;              bm = g;      }  // 8 x 32
  const int wr = w >> 2, wc = w & 3;
  const int q16 = lane >> 4;
  const int l15 = lane & 15;

  // staging sources (pre-swizzled; LDS dest linear).
  const int aIdx = (w << 6) + lane;
  const int aRow = aIdx >> 2, aCph = aIdx & 3;
  const unsigned short* aSrc = A + (size_t)((bm << 7) + aRow) * 2048
                                 + ((aCph ^ ((aRow >> 1) & 3)) << 3);
  const unsigned short* bSrc0 = Bt + (size_t)((bn << 8) + aRow) * 2048
                                  + ((aCph ^ ((aRow >> 1) & 3)) << 3);
  const int bIdx1 = 512 + aIdx;
  const int bRow1 = bIdx1 >> 2, bCph1 = bIdx1 & 3;
  const unsigned short* bSrc1 = Bt + (size_t)((bn << 8) + bRow1) * 2048
                                  + ((bCph1 ^ ((bRow1 >> 1) & 3)) << 3);

  // ds_read offsets (slot-relative)
  const int swx  = ((q16 ^ ((l15 >> 1) & 3)) << 4);
  const int aoff = ((wr << 6) + l15) * 64 + swx;           // + mi*1024
  const int boff = 8192 + ((wc << 6) + l15) * 64 + swx;    // + ni*1024

  f32x4 acc[4][4];
#pragma unroll
  for (int i = 0; i < 4; ++i)
#pragma unroll
    for (int j = 0; j < 4; ++j) acc[i][j] = (f32x4){0.f, 0.f, 0.f, 0.f};

  auto stageT = [&](int t, int slot) {
    char* sb = smem + slot * 24576 + (w << 10);
    const size_t ko = (size_t)t << 5;
    llds16(aSrc + ko, sb);
    llds16(bSrc0 + ko, sb + 8192);
    llds16(bSrc1 + ko, sb + 16384);
  };

  bf16x8 fa0[4], fb0[4], fa1[4], fb1[4];
  auto readFrags = [&](int slot, bf16x8* af, bf16x8* bf) {
    const char* base = smem + slot * 24576;
#pragma unroll
    for (int mi = 0; mi < 4; ++mi) af[mi] = *(const bf16x8*)(base + aoff + (mi << 10));
#pragma unroll
    for (int ni = 0; ni < 4; ++ni) bf[ni] = *(const bf16x8*)(base + boff + (ni << 10));
  };
  auto mfmaStep = [&](bf16x8* af, bf16x8* bf) {
    __builtin_amdgcn_s_setprio(1);
#pragma unroll
    for (int mi = 0; mi < 4; ++mi)
#pragma unroll
      for (int ni = 0; ni < 4; ++ni)
        acc[mi][ni] = __builtin_amdgcn_mfma_f32_16x16x32_bf16(af[mi], bf[ni], acc[mi][ni], 0, 0, 0);
    __builtin_amdgcn_s_setprio(0);
  };
  auto pipeStep = [&](int u, bf16x8* ca, bf16x8* cb, bf16x8* na, bf16x8* nb) {
    asm volatile("s_waitcnt vmcnt(3)" ::: "memory");   // tile u+1 landed (own)
    asm volatile("s_barrier" ::: "memory");            // all waves: u+1 ready
    stageT(u + 3, (u + 3) & 3);                        // overwrite slot of u-1
    readFrags((u + 1) & 3, na, nb);                    // overlaps MFMA below
    mfmaStep(ca, cb);
  };

  // prologue: stage tiles 0,1,2; ensure 0 landed; read its fragments.
  stageT(0, 0); stageT(1, 1); stageT(2, 2);
  asm volatile("s_waitcnt vmcnt(6)" ::: "memory");
  asm volatile("s_barrier" ::: "memory");
  readFrags(0, fa0, fb0);

  pipeStep(0, fa0, fb0, fa1, fb1);
#pragma unroll 1
  for (int u = 1; u < 61; u += 2) {
    pipeStep(u,     fa1, fb1, fa0, fb0);
    pipeStep(u + 1, fa0, fb0, fa1, fb1);
  }
  // tail: u=61 (cur fa1), u=62 (cur fa0), u=63 (cur fa1)
  asm volatile("s_waitcnt vmcnt(3)" ::: "memory");     // tile 62 landed
  asm volatile("s_barrier" ::: "memory");
  readFrags(2, fa0, fb0);
  mfmaStep(fa1, fb1);
  asm volatile("s_waitcnt vmcnt(0)" ::: "memory");     // tile 63 landed
  asm volatile("s_barrier" ::: "memory");
  readFrags(3, fa1, fb1);
  mfmaStep(fa0, fb0);
  mfmaStep(fa1, fb1);

  // epilogue. C/D layout: col = lane&15, row = (lane>>4)*4 + reg  [m89]
  const float qscale = 0.02209708691207961f;   // 1/sqrt(2048)
  const int rb = q16 << 2;
#pragma unroll
  for (int mi = 0; mi < 4; ++mi) {
    int m0 = (bm << 7) + (wr << 6) + (mi << 4) + rb;
#pragma unroll
    for (int ni = 0; ni < 4; ++ni) {
      if constexpr (EPI == 0) {
        int region = bn >> 3;                               // 0 Q, 1 K, 2 V
        int nloc = ((bn & 7) << 8) + (wc << 6) + (ni << 4) + l15;
        if (region == 0) {
#pragma unroll
          for (int j = 0; j < 4; ++j)
            Qb[(size_t)(m0 + j) * 2048 + nloc] = f2bf(acc[mi][ni][j] * qscale);
        } else if (region == 1) {
#pragma unroll
          for (int j = 0; j < 4; ++j)
            Kb[(size_t)(m0 + j) * 2048 + nloc] = f2bf(acc[mi][ni][j]);
        } else {
          u16x4 pk;
#pragma unroll
          for (int j = 0; j < 4; ++j) pk[j] = f2bf(acc[mi][ni][j]);
          int b = m0 >> 11, t = m0 & 2047;
          *(u16x4*)(Vt + ((size_t)((b << 4) + (nloc >> 7)) * 128 + (nloc & 127)) * 2048 + t) = pk;
        }
      } else {
        int n = (bn << 8) + (wc << 6) + (ni << 4) + l15;
#pragma unroll
        for (int j = 0; j < 4; ++j)
          Co[(size_t)(m0 + j) * 2048 + n] = acc[mi][ni][j];
      }
    }
  }
}

// ---------------------------------------------------------------------------
// V suffix sums at 32-row granularity.
// Suf[j][bh][d] = sum_{s >= 32j} V[b, s, h, d],  j in 0..64 (Suf[64] = 0).
// ---------------------------------------------------------------------------
__global__ __launch_bounds__(256) void vsuf_kernel(const unsigned short* __restrict__ Vt,
                                                   float* __restrict__ Suf) {
  const int row  = blockIdx.x * 4 + (threadIdx.x >> 6);  // 0..4095
  const int lane = threadIdx.x & 63;
  const unsigned short* vp = Vt + (size_t)row * 2048 + (lane << 5);
  float a = 0.f;
#pragma unroll
  for (int c = 0; c < 4; ++c) {
    bf16x8 v = *(const bf16x8*)(vp + (c << 3));
#pragma unroll
    for (int j = 0; j < 8; ++j) a += bf2f((unsigned short)v[j]);
  }
  float I = a;
#pragma unroll
  for (int off = 1; off < 64; off <<= 1) {
    float t = __shfl_down(I, off, 64);
    I += (lane + off < 64) ? t : 0.f;
  }
  Suf[(size_t)lane * 4096 + row] = I;
  if (lane == 0) Suf[(size_t)64 * 4096 + row] = 0.f;
}

// ---------------------------------------------------------------------------
// Fused attention, causal-skipped. Flat grid 1024; decode:
//   xcd = f&7, bh = xcd*4 + ((f>>3)&3), strip = 31 - (f>>5)  (LPT order)
// Q is PRE-SCALED by 1/sqrt(T) (folded into projection epilogue).
// Mask/cndmask only on the straddling tile (s0+31 > t0); earlier tiles are
// fully unmasked -> __expf directly. Tiles above the diagonal covered by
// precomputed V-suffix sums (p == 1 exactly there).
// ---------------------------------------------------------------------------
__global__ __launch_bounds__(256) void attn_kernel(const unsigned short* __restrict__ Q,
                                                   const unsigned short* __restrict__ K,
                                                   const unsigned short* __restrict__ V,  // Vt layout
                                                   const float* __restrict__ Suf,
                                                   unsigned short* __restrict__ O) {
  __shared__ __align__(16) char smem[36864];  // K dbuf 2x8K | V dbuf 2x8K | P 4x1K
  const int tid  = threadIdx.x;
  const int lane = tid & 63;
  const int w    = tid >> 6;
  const int q16  = lane >> 4;
  const int l15  = lane & 15;
  const int f    = blockIdx.x;
  const int bh    = ((f & 7) << 2) + ((f >> 3) & 3);
  const int strip = 31 - (f >> 5);
  const int b  = bh >> 4;
  const size_t qkbase = ((size_t)(b << 11)) * 2048 + ((size_t)(bh & 15) << 7);
  const size_t vbase  = (size_t)bh << 18;     // bh*128*2048
  const int rb = q16 << 2;
  char* Psm = smem + 32768 + (w << 10);

  const int numIter = 2 * strip + 2;
  const int t0 = (strip << 6) + (w << 4);

  auto stage = [&](int s0, int kb, int vb) {
#pragma unroll
    for (int c = 0; c < 2; ++c) {
      int ch = (w << 1) + c;
      int rowK = (ch << 2) + q16;                        // 4 rows / 1KB chunk
      int colbK = (l15 << 4) ^ ((rowK & 7) << 4);
      llds16(K + qkbase + (size_t)(s0 + rowK) * 2048 + (colbK >> 1), smem + kb + (ch << 10));
      int rowV = (ch << 4) + (lane >> 2);                // 16 rows / 1KB chunk
      int colbV = ((lane & 3) << 4) ^ (((rowV >> 2) & 3) << 4);
      llds16(V + vbase + (size_t)rowV * 2048 + s0 + (colbV >> 1), smem + vb + (ch << 10));
    }
  };

  // Q fragments: lane holds Q[t0 + (lane&15)][8*(lane>>4) + j + 32*kk]
  bf16x8 qf[4];
  {
    const unsigned short* qp = Q + qkbase + (size_t)(t0 + l15) * 2048 + (q16 << 3);
#pragma unroll
    for (int kk = 0; kk < 4; ++kk) qf[kk] = *(const bf16x8*)(qp + (kk << 5));
  }

  f32x4 oacc[8];
#pragma unroll
  for (int i = 0; i < 8; ++i) oacc[i] = (f32x4){0.f, 0.f, 0.f, 0.f};
  float ell[4] = {0.f, 0.f, 0.f, 0.f};   // per-lane partial; reduced in epilogue

  stage(0, 0, 16384);
  asm volatile("s_waitcnt vmcnt(0)" ::: "memory");
  __syncthreads();

  int cur = 0;
  for (int it = 0; it < numIter; ++it) {
    const int s0 = it << 5;
    if (it + 1 < numIter)
      stage(s0 + 32, (cur ^ 1) << 13, 16384 + ((cur ^ 1) << 13));

    if (s0 <= t0) {   // tile not entirely above this wave's diagonal
      const int kb = cur << 13;
      const int vb = 16384 + (cur << 13);

      // QK^T: two 16-col s-tiles (scores already scaled via Q)
      f32x4 sA = (f32x4){0.f, 0.f, 0.f, 0.f}, sB = (f32x4){0.f, 0.f, 0.f, 0.f};
#pragma unroll
      for (int kk = 0; kk < 4; ++kk) {
        int r0 = l15;
        bf16x8 k0f = *(const bf16x8*)(smem + kb + (r0 << 8) + (((kk << 6) + (q16 << 4)) ^ ((r0 & 7) << 4)));
        sA = __builtin_amdgcn_mfma_f32_16x16x32_bf16(qf[kk], k0f, sA, 0, 0, 0);
        int r1 = 16 + l15;
        bf16x8 k1f = *(const bf16x8*)(smem + kb + (r1 << 8) + (((kk << 6) + (q16 << 4)) ^ ((r1 & 7) << 4)));
        sB = __builtin_amdgcn_mfma_f32_16x16x32_bf16(qf[kk], k1f, sB, 0, 0, 0);
      }

      float pA[4], pB[4];
      if (s0 + 31 <= t0) {           // fully unmasked tile (the common case)
#pragma unroll
        for (int j = 0; j < 4; ++j) {
          pA[j] = __expf(sA[j]);
          pB[j] = __expf(sB[j]);
          ell[j] += pA[j] + pB[j];
        }
      } else {                       // straddling tile: mask -> exp(0)=1
#pragma unroll
        for (int j = 0; j < 4; ++j) {
          int t  = t0 + rb + j;
          int sa = s0 + l15;
          float vA = (sa <= t)      ? sA[j] : 0.f;
          float vB = (sa + 16 <= t) ? sB[j] : 0.f;
          pA[j] = __expf(vA);
          pB[j] = __expf(vB);
          ell[j] += pA[j] + pB[j];
        }
      }

      // P -> per-wave LDS [16 t][32 s] bf16, swz: col ^= ((row>>1)&3)<<4
#pragma unroll
      for (int j = 0; j < 4; ++j) {
        int r   = rb + j;
        int swz = ((r >> 1) & 3) << 4;
        *(unsigned short*)(Psm + (r << 6) + ((l15 << 1) ^ swz))        = f2bfru(pA[j]);
        *(unsigned short*)(Psm + (r << 6) + ((32 + (l15 << 1)) ^ swz)) = f2bfru(pB[j]);
      }
      asm volatile("s_waitcnt lgkmcnt(0)" ::: "memory");

      bf16x8 pa;
      {
        int r = l15;
        pa = *(const bf16x8*)(Psm + (r << 6) + ((q16 << 4) ^ (((r >> 1) & 3) << 4)));
      }
#pragma unroll
      for (int ni = 0; ni < 8; ++ni) {
        int dr = (ni << 4) + l15;
        bf16x8 vbf = *(const bf16x8*)(smem + vb + (dr << 6) + ((q16 << 4) ^ (((dr >> 2) & 3) << 4)));
        oacc[ni] = __builtin_amdgcn_mfma_f32_16x16x32_bf16(pa, vbf, oacc[ni], 0, 0, 0);
      }
    }

    asm volatile("s_waitcnt vmcnt(0)" ::: "memory");
    __syncthreads();
    cur ^= 1;
  }

  // suffix correction: all s >= send have p == 1 exactly.
  const int send = (t0 & ~31) + 32;
  const float* sp = Suf + (size_t)(send >> 5) * 4096 + ((size_t)bh << 7);
  const float extra = (float)(2048 - send);
#pragma unroll
  for (int ni = 0; ni < 8; ++ni) {
    float sv = sp[(ni << 4) + l15];
#pragma unroll
    for (int j = 0; j < 4; ++j) oacc[ni][j] += sv;
  }

  // deferred ell reduction (within each 16-lane row group), then normalize
#pragma unroll
  for (int j = 0; j < 4; ++j) {
    float r = ell[j];
    r += __shfl_xor(r, 1, 64);
    r += __shfl_xor(r, 2, 64);
    r += __shfl_xor(r, 4, 64);
    r += __shfl_xor(r, 8, 64);
    float inv = 1.0f / (r + extra);
    int t = t0 + rb + j;
    unsigned short* op = O + qkbase + (size_t)t * 2048;
#pragma unroll
    for (int ni = 0; ni < 8; ++ni)
      op[(ni << 4) + l15] = f2bf(oacc[ni][j] * inv);
  }
}

// ---------------------------------------------------------------------------
// launch
// ---------------------------------------------------------------------------
extern "C" void kernel_launch(void* const* d_in, const int* in_sizes, int n_in,
                              void* d_out, int out_size, void* d_ws, size_t ws_size,
                              hipStream_t stream) {
  (void)in_sizes; (void)n_in; (void)out_size; (void)ws_size;
  const float* x  = (const float*)d_in[0];
  const float* Wq = (const float*)d_in[1];
  const float* Wk = (const float*)d_in[2];
  const float* Wv = (const float*)d_in[3];
  const float* Wo = (const float*)d_in[4];
  float* out = (float*)d_out;

  char* ws = (char*)d_ws;
  unsigned short* Xb  = (unsigned short*)(ws);                        // 16 MiB (reused as O)
  unsigned short* Wqt = (unsigned short*)(ws + 16777216);             // 8 MiB (reused as Suf)
  unsigned short* Wkt = (unsigned short*)(ws + 16777216 + 8388608);
  unsigned short* Wvt = (unsigned short*)(ws + 16777216 + 2 * 8388608);
  unsigned short* Wot = (unsigned short*)(ws + 16777216 + 3 * 8388608);
  unsigned short* Qb  = (unsigned short*)(ws + 50331648);             // 16 MiB
  unsigned short* Kb  = (unsigned short*)(ws + 67108864);             // 16 MiB
  unsigned short* Vt  = (unsigned short*)(ws + 83886080);             // 16 MiB
  unsigned short* Ob  = Xb;          // X dead after the QKV projection
  float*          Suf = (float*)Wqt; // W^T dead after the QKV projection

  cast_x_kernel<<<8192, 256, 0, stream>>>(x, Xb);
  {
    dim3 tb(32, 8), tg(64, 64, 4);
    transpose_w4_kernel<<<tg, tb, 0, stream>>>(Wq, Wk, Wv, Wo, Wqt, Wkt, Wvt, Wot);
  }
  // fused QKV projection: Bt = [Wqt|Wkt|Wvt] (contiguous), N=6144
  gemm_pipe<0><<<768, 512, 0, stream>>>(Xb, Wqt, Qb, Kb, Vt, nullptr);

  vsuf_kernel<<<1024, 256, 0, stream>>>(Vt, Suf);

  attn_kernel<<<1024, 256, 0, stream>>>(Qb, Kb, Vt, Suf, Ob);

  gemm_pipe<1><<<256, 512, 0, stream>>>(Ob, Wot, nullptr, nullptr, nullptr, out);
}

// Round 6
// 261.613 us; speedup vs baseline: 1.4639x; 1.0154x over previous
//
#include <hip/hip_runtime.h>

// ---------------------------------------------------------------------------
// MultiHeadAttention forward, MI355X/gfx950.
// B=2, T=2048, D=2048, H=16, Dh=128. fp32 in/out, bf16 MFMA internally.
// Reference quirks (faithful): multiplicative tril mask (masked scores = 0,
// NOT -inf -> exp(0)=1 contributions over ALL 2048 cols), scale = 1/sqrt(T).
// Round 6: GEMM -> 128x64 wave tile (FLOP/LDS-byte 42.7 vs 32), 4-wave
// blocks, ring-3 LDS (72KB -> 2 blocks/CU), ONE barrier + counted vmcnt(6)
// per K-step. QKV fused (grid 768), Wo BN=128 (grid 512). Attn unchanged.
// ---------------------------------------------------------------------------

typedef __attribute__((ext_vector_type(4))) float  f32x4;
typedef __attribute__((ext_vector_type(8))) short  bf16x8;
typedef __attribute__((ext_vector_type(4))) unsigned short u16x4;

#define AS1 __attribute__((address_space(1)))
#define AS3 __attribute__((address_space(3)))

__device__ __forceinline__ void llds16(const void* g, void* l) {
  __builtin_amdgcn_global_load_lds((const AS1 void*)g, (AS3 void*)l, 16, 0, 0);
}

__device__ __forceinline__ unsigned short f2bf(float f) {   // RNE
  unsigned int u = __builtin_bit_cast(unsigned int, f);
  u += 0x7fffu + ((u >> 16) & 1u);
  return (unsigned short)(u >> 16);
}

__device__ __forceinline__ unsigned short f2bfru(float f) { // round-half-up
  return (unsigned short)((__builtin_bit_cast(unsigned int, f) + 0x8000u) >> 16);
}

__device__ __forceinline__ float bf2f(unsigned short u) {
  return __builtin_bit_cast(float, (unsigned int)u << 16);
}

// ---------------------------------------------------------------------------
// cast x (fp32) -> bf16, 4 elements/thread
// ---------------------------------------------------------------------------
__global__ __launch_bounds__(256) void cast_x_kernel(const float* __restrict__ in,
                                                     unsigned short* __restrict__ out) {
  int i = blockIdx.x * 256 + threadIdx.x;
  f32x4 v = ((const f32x4*)in)[i];
  u16x4 o;
  o[0] = f2bf(v[0]); o[1] = f2bf(v[1]); o[2] = f2bf(v[2]); o[3] = f2bf(v[3]);
  ((u16x4*)out)[i] = o;
}

// ---------------------------------------------------------------------------
// 4 weight transposes in one launch. W [2048][2048] fp32 -> Wt[n][k] bf16.
// ---------------------------------------------------------------------------
__global__ __launch_bounds__(256) void transpose_w4_kernel(
    const float* __restrict__ W0, const float* __restrict__ W1,
    const float* __restrict__ W2, const float* __restrict__ W3,
    unsigned short* __restrict__ T0, unsigned short* __restrict__ T1,
    unsigned short* __restrict__ T2, unsigned short* __restrict__ T3) {
  __shared__ float tile[32][33];
  const int z = blockIdx.z;
  const float* W = (z == 0) ? W0 : (z == 1) ? W1 : (z == 2) ? W2 : W3;
  unsigned short* Wt = (z == 0) ? T0 : (z == 1) ? T1 : (z == 2) ? T2 : T3;
  const int bx = blockIdx.x << 5;   // k base
  const int by = blockIdx.y << 5;   // n base
  const int tx = threadIdx.x;       // 0..31
  const int ty = threadIdx.y;       // 0..7
#pragma unroll
  for (int r = ty; r < 32; r += 8)
    tile[r][tx] = W[(size_t)(bx + r) * 2048 + by + tx];
  __syncthreads();
#pragma unroll
  for (int r = ty; r < 32; r += 8)
    Wt[(size_t)(by + r) * 2048 + bx + tx] = f2bf(tile[tx][r]);
}

// ---------------------------------------------------------------------------
// bf16 GEMM, C[M][N] = A[M][K] @ Bt[N][K]^T, K=2048, M=4096.
// 4 waves (256 thr), BK=32, ring-3 LDS slots, 1 barrier + vmcnt(6|4)/step.
// EPI 0: QKV fused. BM=128, BN=256, wave tile 128x64 (1Mx4N). grid 768.
//        bn 0-7 -> Q (scaled 1/sqrt(T)), 8-15 -> K, 16-23 -> V^T scatter.
// EPI 1: Wo, fp32 out. BM=128, BN=128, wave tile 64x64 (2Mx2N). grid 512.
// ---------------------------------------------------------------------------
template <int EPI>
__global__ __launch_bounds__(256, 2) void gemm_pipe(const unsigned short* __restrict__ A,
                                                    const unsigned short* __restrict__ Bt,
                                                    unsigned short* __restrict__ Qb,
                                                    unsigned short* __restrict__ Kb,
                                                    unsigned short* __restrict__ Vt,
                                                    float* __restrict__ Co) {
  constexpr int BN      = (EPI == 0) ? 256 : 128;
  constexpr int MI      = (EPI == 0) ? 8 : 4;       // A frags / wave
  constexpr int BROUNDS = BN / 64;                  // B stage rounds
  constexpr int SLOT    = 8192 + BN * 64;           // A 8KB + B BN*32*2
  __shared__ __align__(16) char smem[3 * SLOT];

  const int tid  = threadIdx.x;
  const int lane = tid & 63;
  const int w    = tid >> 6;                        // 0..3
  const int q16  = lane >> 4;
  const int l15  = lane & 15;
  const int f    = blockIdx.x;
  const int g    = f >> 3;
  int bm, bn;
  if constexpr (EPI == 0) { bn = (f & 7) * 3 + (g % 3); bm = g / 3; }   // 24 x 32
  else                    { bn = ((f & 7) << 1) + (g & 1); bm = g >> 1; } // 16 x 32
  const int wmb = (EPI == 0) ? 0 : ((w >> 1) << 6);        // wave m base
  const int wnb = (EPI == 0) ? (w << 6) : ((w & 1) << 6);  // wave n base

  f32x4 acc[MI][4];
#pragma unroll
  for (int i = 0; i < MI; ++i)
#pragma unroll
    for (int j = 0; j < 4; ++j) acc[i][j] = (f32x4){0.f, 0.f, 0.f, 0.f};

  // staging: BK=32 -> 64B rows, 4 chunks of 16B; swizzle chunk ^= (row>>1)&3.
  // thread tid covers row = r*64 + tid/4, phys chunk = tid&3; LDS dest is
  // linear (= wave-uniform base + lane*16), global source pre-swizzled.
  const int rowA = tid >> 2;
  const int chA  = tid & 3;
  auto stageT = [&](int t, char* sb) {
    const int k0 = t << 5;
#pragma unroll
    for (int r = 0; r < 2; ++r) {
      int row = (r << 6) + rowA;
      const unsigned short* src = A + (size_t)((bm << 7) + row) * 2048 + k0
                                    + ((chA ^ ((row >> 1) & 3)) << 3);
      llds16(src, sb + (r << 12) + (w << 10));
    }
#pragma unroll
    for (int r = 0; r < BROUNDS; ++r) {
      int row = (r << 6) + rowA;
      const unsigned short* src = Bt + (size_t)(bn * BN + row) * 2048 + k0
                                     + ((chA ^ ((row >> 1) & 3)) << 3);
      llds16(src, sb + 8192 + (r << 12) + (w << 10));
    }
  };

  auto computeT = [&](const char* base) {
    bf16x8 af[MI], bf[4];
#pragma unroll
    for (int mi = 0; mi < MI; ++mi) {
      int row = wmb + (mi << 4) + l15;
      af[mi] = *(const bf16x8*)(base + (row << 6) + ((q16 ^ ((row >> 1) & 3)) << 4));
    }
#pragma unroll
    for (int ni = 0; ni < 4; ++ni) {
      int row = wnb + (ni << 4) + l15;
      bf[ni] = *(const bf16x8*)(base + 8192 + (row << 6) + ((q16 ^ ((row >> 1) & 3)) << 4));
    }
    __builtin_amdgcn_s_setprio(1);
#pragma unroll
    for (int mi = 0; mi < MI; ++mi)
#pragma unroll
      for (int ni = 0; ni < 4; ++ni)
        acc[mi][ni] = __builtin_amdgcn_mfma_f32_16x16x32_bf16(af[mi], bf[ni], acc[mi][ni], 0, 0, 0);
    __builtin_amdgcn_s_setprio(0);
  };

  auto WAITC = [&]() {
    if constexpr (EPI == 0) asm volatile("s_waitcnt vmcnt(6)" ::: "memory");
    else                    asm volatile("s_waitcnt vmcnt(4)" ::: "memory");
  };
  auto STEP = [&](int t, char* cbase, char* sbase) {
    WAITC();                                 // tile t landed (own wave's loads)
    __builtin_amdgcn_s_barrier();            // all waves' loads for t landed
    stageT(t + 2, sbase);                    // issue next-next tile
    computeT(cbase);                         // ds_read + MFMA (compiler lgkmcnt)
  };

  char* s0 = smem;
  char* s1 = smem + SLOT;
  char* s2 = smem + 2 * SLOT;

  // prologue: tiles 0,1 in flight
  stageT(0, s0); stageT(1, s1);

  // main: t = 0..61 (stages up to tile 63), slots rotate mod 3
#pragma unroll 1
  for (int t = 0; t < 60; t += 3) {
    STEP(t,     s0, s2);
    STEP(t + 1, s1, s0);
    STEP(t + 2, s2, s1);
  }
  STEP(60, s0, s2);
  STEP(61, s1, s0);
  // tail: t=62 (slot2), t=63 (slot0); exact-count drains
  WAITC();
  __builtin_amdgcn_s_barrier();
  computeT(s2);
  asm volatile("s_waitcnt vmcnt(0)" ::: "memory");
  __builtin_amdgcn_s_barrier();
  computeT(s0);

  // epilogue. C/D layout: col = lane&15, row = (lane>>4)*4 + reg  [m89]
  const float qscale = 0.02209708691207961f;   // 1/sqrt(2048)
  const int rb = q16 << 2;
#pragma unroll
  for (int mi = 0; mi < MI; ++mi) {
    int m0 = (bm << 7) + wmb + (mi << 4) + rb;
#pragma unroll
    for (int ni = 0; ni < 4; ++ni) {
      if constexpr (EPI == 0) {
        int region = bn >> 3;                               // 0 Q, 1 K, 2 V
        int nloc = ((bn & 7) << 8) + wnb + (ni << 4) + l15;
        if (region == 0) {
#pragma unroll
          for (int j = 0; j < 4; ++j)
            Qb[(size_t)(m0 + j) * 2048 + nloc] = f2bf(acc[mi][ni][j] * qscale);
        } else if (region == 1) {
#pragma unroll
          for (int j = 0; j < 4; ++j)
            Kb[(size_t)(m0 + j) * 2048 + nloc] = f2bf(acc[mi][ni][j]);
        } else {
          u16x4 pk;
#pragma unroll
          for (int j = 0; j < 4; ++j) pk[j] = f2bf(acc[mi][ni][j]);
          int b = m0 >> 11, t = m0 & 2047;
          *(u16x4*)(Vt + ((size_t)((b << 4) + (nloc >> 7)) * 128 + (nloc & 127)) * 2048 + t) = pk;
        }
      } else {
        int n = (bn << 7) + wnb + (ni << 4) + l15;
#pragma unroll
        for (int j = 0; j < 4; ++j)
          Co[(size_t)(m0 + j) * 2048 + n] = acc[mi][ni][j];
      }
    }
  }
}

// ---------------------------------------------------------------------------
// V suffix sums at 32-row granularity.
// Suf[j][bh][d] = sum_{s >= 32j} V[b, s, h, d],  j in 0..64 (Suf[64] = 0).
// ---------------------------------------------------------------------------
__global__ __launch_bounds__(256) void vsuf_kernel(const unsigned short* __restrict__ Vt,
                                                   float* __restrict__ Suf) {
  const int row  = blockIdx.x * 4 + (threadIdx.x >> 6);  // 0..4095
  const int lane = threadIdx.x & 63;
  const unsigned short* vp = Vt + (size_t)row * 2048 + (lane << 5);
  float a = 0.f;
#pragma unroll
  for (int c = 0; c < 4; ++c) {
    bf16x8 v = *(const bf16x8*)(vp + (c << 3));
#pragma unroll
    for (int j = 0; j < 8; ++j) a += bf2f((unsigned short)v[j]);
  }
  float I = a;
#pragma unroll
  for (int off = 1; off < 64; off <<= 1) {
    float t = __shfl_down(I, off, 64);
    I += (lane + off < 64) ? t : 0.f;
  }
  Suf[(size_t)lane * 4096 + row] = I;
  if (lane == 0) Suf[(size_t)64 * 4096 + row] = 0.f;
}

// ---------------------------------------------------------------------------
// Fused attention, causal-skipped. Flat grid 1024; decode:
//   xcd = f&7, bh = xcd*4 + ((f>>3)&3), strip = 31 - (f>>5)  (LPT order)
// Q is PRE-SCALED by 1/sqrt(T). Mask only on the straddling tile. Tiles
// above the diagonal covered by V-suffix sums (p == 1 exactly there).
// ---------------------------------------------------------------------------
__global__ __launch_bounds__(256) void attn_kernel(const unsigned short* __restrict__ Q,
                                                   const unsigned short* __restrict__ K,
                                                   const unsigned short* __restrict__ V,  // Vt layout
                                                   const float* __restrict__ Suf,
                                                   unsigned short* __restrict__ O) {
  __shared__ __align__(16) char smem[36864];  // K dbuf 2x8K | V dbuf 2x8K | P 4x1K
  const int tid  = threadIdx.x;
  const int lane = tid & 63;
  const int w    = tid >> 6;
  const int q16  = lane >> 4;
  const int l15  = lane & 15;
  const int f    = blockIdx.x;
  const int bh    = ((f & 7) << 2) + ((f >> 3) & 3);
  const int strip = 31 - (f >> 5);
  const int b  = bh >> 4;
  const size_t qkbase = ((size_t)(b << 11)) * 2048 + ((size_t)(bh & 15) << 7);
  const size_t vbase  = (size_t)bh << 18;     // bh*128*2048
  const int rb = q16 << 2;
  char* Psm = smem + 32768 + (w << 10);

  const int numIter = 2 * strip + 2;
  const int t0 = (strip << 6) + (w << 4);

  auto stage = [&](int s0, int kb, int vb) {
#pragma unroll
    for (int c = 0; c < 2; ++c) {
      int ch = (w << 1) + c;
      int rowK = (ch << 2) + q16;                        // 4 rows / 1KB chunk
      int colbK = (l15 << 4) ^ ((rowK & 7) << 4);
      llds16(K + qkbase + (size_t)(s0 + rowK) * 2048 + (colbK >> 1), smem + kb + (ch << 10));
      int rowV = (ch << 4) + (lane >> 2);                // 16 rows / 1KB chunk
      int colbV = ((lane & 3) << 4) ^ (((rowV >> 2) & 3) << 4);
      llds16(V + vbase + (size_t)rowV * 2048 + s0 + (colbV >> 1), smem + vb + (ch << 10));
    }
  };

  // Q fragments: lane holds Q[t0 + (lane&15)][8*(lane>>4) + j + 32*kk]
  bf16x8 qf[4];
  {
    const unsigned short* qp = Q + qkbase + (size_t)(t0 + l15) * 2048 + (q16 << 3);
#pragma unroll
    for (int kk = 0; kk < 4; ++kk) qf[kk] = *(const bf16x8*)(qp + (kk << 5));
  }

  f32x4 oacc[8];
#pragma unroll
  for (int i = 0; i < 8; ++i) oacc[i] = (f32x4){0.f, 0.f, 0.f, 0.f};
  float ell[4] = {0.f, 0.f, 0.f, 0.f};   // per-lane partial; reduced in epilogue

  stage(0, 0, 16384);
  asm volatile("s_waitcnt vmcnt(0)" ::: "memory");
  __syncthreads();

  int cur = 0;
  for (int it = 0; it < numIter; ++it) {
    const int s0 = it << 5;
    if (it + 1 < numIter)
      stage(s0 + 32, (cur ^ 1) << 13, 16384 + ((cur ^ 1) << 13));

    if (s0 <= t0) {   // tile not entirely above this wave's diagonal
      const int kb = cur << 13;
      const int vb = 16384 + (cur << 13);

      // QK^T: two 16-col s-tiles (scores already scaled via Q)
      f32x4 sA = (f32x4){0.f, 0.f, 0.f, 0.f}, sB = (f32x4){0.f, 0.f, 0.f, 0.f};
#pragma unroll
      for (int kk = 0; kk < 4; ++kk) {
        int r0 = l15;
        bf16x8 k0f = *(const bf16x8*)(smem + kb + (r0 << 8) + (((kk << 6) + (q16 << 4)) ^ ((r0 & 7) << 4)));
        sA = __builtin_amdgcn_mfma_f32_16x16x32_bf16(qf[kk], k0f, sA, 0, 0, 0);
        int r1 = 16 + l15;
        bf16x8 k1f = *(const bf16x8*)(smem + kb + (r1 << 8) + (((kk << 6) + (q16 << 4)) ^ ((r1 & 7) << 4)));
        sB = __builtin_amdgcn_mfma_f32_16x16x32_bf16(qf[kk], k1f, sB, 0, 0, 0);
      }

      float pA[4], pB[4];
      if (s0 + 31 <= t0) {           // fully unmasked tile (the common case)
#pragma unroll
        for (int j = 0; j < 4; ++j) {
          pA[j] = __expf(sA[j]);
          pB[j] = __expf(sB[j]);
          ell[j] += pA[j] + pB[j];
        }
      } else {                       // straddling tile: mask -> exp(0)=1
#pragma unroll
        for (int j = 0; j < 4; ++j) {
          int t  = t0 + rb + j;
          int sa = s0 + l15;
          float vA = (sa <= t)      ? sA[j] : 0.f;
          float vB = (sa + 16 <= t) ? sB[j] : 0.f;
          pA[j] = __expf(vA);
          pB[j] = __expf(vB);
          ell[j] += pA[j] + pB[j];
        }
      }

      // P -> per-wave LDS [16 t][32 s] bf16, swz: col ^= ((row>>1)&3)<<4
#pragma unroll
      for (int j = 0; j < 4; ++j) {
        int r   = rb + j;
        int swz = ((r >> 1) & 3) << 4;
        *(unsigned short*)(Psm + (r << 6) + ((l15 << 1) ^ swz))        = f2bfru(pA[j]);
        *(unsigned short*)(Psm + (r << 6) + ((32 + (l15 << 1)) ^ swz)) = f2bfru(pB[j]);
      }
      asm volatile("s_waitcnt lgkmcnt(0)" ::: "memory");

      bf16x8 pa;
      {
        int r = l15;
        pa = *(const bf16x8*)(Psm + (r << 6) + ((q16 << 4) ^ (((r >> 1) & 3) << 4)));
      }
#pragma unroll
      for (int ni = 0; ni < 8; ++ni) {
        int dr = (ni << 4) + l15;
        bf16x8 vbf = *(const bf16x8*)(smem + vb + (dr << 6) + ((q16 << 4) ^ (((dr >> 2) & 3) << 4)));
        oacc[ni] = __builtin_amdgcn_mfma_f32_16x16x32_bf16(pa, vbf, oacc[ni], 0, 0, 0);
      }
    }

    asm volatile("s_waitcnt vmcnt(0)" ::: "memory");
    __syncthreads();
    cur ^= 1;
  }

  // suffix correction: all s >= send have p == 1 exactly.
  const int send = (t0 & ~31) + 32;
  const float* sp = Suf + (size_t)(send >> 5) * 4096 + ((size_t)bh << 7);
  const float extra = (float)(2048 - send);
#pragma unroll
  for (int ni = 0; ni < 8; ++ni) {
    float sv = sp[(ni << 4) + l15];
#pragma unroll
    for (int j = 0; j < 4; ++j) oacc[ni][j] += sv;
  }

  // deferred ell reduction (within each 16-lane row group), then normalize
#pragma unroll
  for (int j = 0; j < 4; ++j) {
    float r = ell[j];
    r += __shfl_xor(r, 1, 64);
    r += __shfl_xor(r, 2, 64);
    r += __shfl_xor(r, 4, 64);
    r += __shfl_xor(r, 8, 64);
    float inv = 1.0f / (r + extra);
    int t = t0 + rb + j;
    unsigned short* op = O + qkbase + (size_t)t * 2048;
#pragma unroll
    for (int ni = 0; ni < 8; ++ni)
      op[(ni << 4) + l15] = f2bf(oacc[ni][j] * inv);
  }
}

// ---------------------------------------------------------------------------
// launch
// ---------------------------------------------------------------------------
extern "C" void kernel_launch(void* const* d_in, const int* in_sizes, int n_in,
                              void* d_out, int out_size, void* d_ws, size_t ws_size,
                              hipStream_t stream) {
  (void)in_sizes; (void)n_in; (void)out_size; (void)ws_size;
  const float* x  = (const float*)d_in[0];
  const float* Wq = (const float*)d_in[1];
  const float* Wk = (const float*)d_in[2];
  const float* Wv = (const float*)d_in[3];
  const float* Wo = (const float*)d_in[4];
  float* out = (float*)d_out;

  char* ws = (char*)d_ws;
  unsigned short* Xb  = (unsigned short*)(ws);                        // 16 MiB (reused as O)
  unsigned short* Wqt = (unsigned short*)(ws + 16777216);             // 8 MiB (reused as Suf)
  unsigned short* Wkt = (unsigned short*)(ws + 16777216 + 8388608);
  unsigned short* Wvt = (unsigned short*)(ws + 16777216 + 2 * 8388608);
  unsigned short* Wot = (unsigned short*)(ws + 16777216 + 3 * 8388608);
  unsigned short* Qb  = (unsigned short*)(ws + 50331648);             // 16 MiB
  unsigned short* Kb  = (unsigned short*)(ws + 67108864);             // 16 MiB
  unsigned short* Vt  = (unsigned short*)(ws + 83886080);             // 16 MiB
  unsigned short* Ob  = Xb;          // X dead after the QKV projection
  float*          Suf = (float*)Wqt; // W^T dead after the QKV projection

  cast_x_kernel<<<8192, 256, 0, stream>>>(x, Xb);
  {
    dim3 tb(32, 8), tg(64, 64, 4);
    transpose_w4_kernel<<<tg, tb, 0, stream>>>(Wq, Wk, Wv, Wo, Wqt, Wkt, Wvt, Wot);
  }
  // fused QKV projection: Bt = [Wqt|Wkt|Wvt] (contiguous), N=6144
  gemm_pipe<0><<<768, 256, 0, stream>>>(Xb, Wqt, Qb, Kb, Vt, nullptr);

  vsuf_kernel<<<1024, 256, 0, stream>>>(Vt, Suf);

  attn_kernel<<<1024, 256, 0, stream>>>(Qb, Kb, Vt, Suf, Ob);

  gemm_pipe<1><<<512, 256, 0, stream>>>(Ob, Wot, nullptr, nullptr, nullptr, out);
}

// Round 7
// 257.022 us; speedup vs baseline: 1.4901x; 1.0179x over previous
//
#include <hip/hip_runtime.h>

// ---------------------------------------------------------------------------
// MultiHeadAttention forward, MI355X/gfx950.
// B=2, T=2048, D=2048, H=16, Dh=128. fp32 in/out, bf16 MFMA internally.
// Reference quirks (faithful): multiplicative tril mask (masked scores = 0,
// NOT -inf -> exp(0)=1 contributions over ALL 2048 cols), scale = 1/sqrt(T).
// Round 7: QKV -> 8-phase fine-interleaved GEMM (m201-class): BM=128 BN=384
// BK=64, 8 waves (wave tile 64x96), dbuf 128KB LDS, per-phase
// {ds_read || stage -> barrier -> 12 MFMA -> barrier}, vmcnt(0) only at
// tile end (loads are 2+ phases old). Grid 512 = exactly 2 full CU rounds.
// Wo + attn unchanged from round 6 (passing).
// ---------------------------------------------------------------------------

typedef __attribute__((ext_vector_type(4))) float  f32x4;
typedef __attribute__((ext_vector_type(8))) short  bf16x8;
typedef __attribute__((ext_vector_type(4))) unsigned short u16x4;

#define AS1 __attribute__((address_space(1)))
#define AS3 __attribute__((address_space(3)))

__device__ __forceinline__ void llds16(const void* g, void* l) {
  __builtin_amdgcn_global_load_lds((const AS1 void*)g, (AS3 void*)l, 16, 0, 0);
}

__device__ __forceinline__ unsigned short f2bf(float f) {   // RNE
  unsigned int u = __builtin_bit_cast(unsigned int, f);
  u += 0x7fffu + ((u >> 16) & 1u);
  return (unsigned short)(u >> 16);
}

__device__ __forceinline__ unsigned short f2bfru(float f) { // round-half-up
  return (unsigned short)((__builtin_bit_cast(unsigned int, f) + 0x8000u) >> 16);
}

__device__ __forceinline__ float bf2f(unsigned short u) {
  return __builtin_bit_cast(float, (unsigned int)u << 16);
}

// ---------------------------------------------------------------------------
// cast x (fp32) -> bf16, 4 elements/thread
// ---------------------------------------------------------------------------
__global__ __launch_bounds__(256) void cast_x_kernel(const float* __restrict__ in,
                                                     unsigned short* __restrict__ out) {
  int i = blockIdx.x * 256 + threadIdx.x;
  f32x4 v = ((const f32x4*)in)[i];
  u16x4 o;
  o[0] = f2bf(v[0]); o[1] = f2bf(v[1]); o[2] = f2bf(v[2]); o[3] = f2bf(v[3]);
  ((u16x4*)out)[i] = o;
}

// ---------------------------------------------------------------------------
// 4 weight transposes in one launch. W [2048][2048] fp32 -> Wt[n][k] bf16.
// ---------------------------------------------------------------------------
__global__ __launch_bounds__(256) void transpose_w4_kernel(
    const float* __restrict__ W0, const float* __restrict__ W1,
    const float* __restrict__ W2, const float* __restrict__ W3,
    unsigned short* __restrict__ T0, unsigned short* __restrict__ T1,
    unsigned short* __restrict__ T2, unsigned short* __restrict__ T3) {
  __shared__ float tile[32][33];
  const int z = blockIdx.z;
  const float* W = (z == 0) ? W0 : (z == 1) ? W1 : (z == 2) ? W2 : W3;
  unsigned short* Wt = (z == 0) ? T0 : (z == 1) ? T1 : (z == 2) ? T2 : T3;
  const int bx = blockIdx.x << 5;   // k base
  const int by = blockIdx.y << 5;   // n base
  const int tx = threadIdx.x;       // 0..31
  const int ty = threadIdx.y;       // 0..7
#pragma unroll
  for (int r = ty; r < 32; r += 8)
    tile[r][tx] = W[(size_t)(bx + r) * 2048 + by + tx];
  __syncthreads();
#pragma unroll
  for (int r = ty; r < 32; r += 8)
    Wt[(size_t)(by + r) * 2048 + bx + tx] = f2bf(tile[tx][r]);
}

// ---------------------------------------------------------------------------
// Fused QKV projection, 8-phase fine-interleaved GEMM.
// C[M=4096][N=6144] = X[M][K=2048] @ Wt[N][K]^T, Wt = [Wq^T|Wk^T|Wv^T].
// BM=128, BN=384, BK=64. 8 waves (2M x 4N), wave tile 64x96 (4mi x 6ni).
// LDS: dbuf x (A 16KB + B 48KB) = 128KB. Per K-tile: 4 phases
//   P(ks,nh): ds_read {A[4] if nh==0, B[3]} || stage 2-3 gloads ->
//   s_barrier -> setprio(1) -> 12 MFMA -> setprio(0) -> s_barrier
// vmcnt(0)+barrier once per tile (staged loads >= 2 phases old -> free).
// LDS rows 128B, chunk swizzle cp = cl ^ (row&7) both sides (conflict-free).
// Grid 512 flat (= 2 exact CU rounds), 2 bn panels per XCD (3MB -> L2).
// Epilogue: region 0 -> Qb * 1/sqrt(T), 1 -> Kb, 2 -> Vt scatter.
// ---------------------------------------------------------------------------
__global__ __launch_bounds__(512, 2) void gemm_qkv8(const unsigned short* __restrict__ A,
                                                    const unsigned short* __restrict__ Bt,
                                                    unsigned short* __restrict__ Qb,
                                                    unsigned short* __restrict__ Kb,
                                                    unsigned short* __restrict__ Vt) {
  __shared__ __align__(16) char smem[131072];
  const int tid  = threadIdx.x;
  const int lane = tid & 63;
  const int w    = tid >> 6;          // 0..7
  const int wr   = w >> 2;            // m-half
  const int wc   = w & 3;             // n-quarter
  const int q16  = lane >> 4;
  const int l15  = lane & 15;
  const int f    = blockIdx.x;
  const int bn   = ((f & 7) << 1) + ((f >> 3) & 1);   // 0..15
  const int bm   = f >> 4;                            // 0..31

  // staging sources: thread covers LDS row srow (+ li*64), phys chunk tid&7,
  // logical chunk = phys ^ (row&7); src = row-major global, pre-swizzled.
  const int srow = tid >> 3;                          // 0..63
  const int scl  = (tid & 7) ^ (srow & 7);
  const unsigned short* aS = A  + (size_t)((bm << 7) + srow) * 2048 + (scl << 3);
  const unsigned short* bS = Bt + (size_t)(bn * 384 + srow) * 2048 + (scl << 3);
  const int sdst = tid << 4;

  // ds_read: row = base + l15, chunk = (ks*4 + q16) ^ (l15&7)
  const int swzb = (q16 ^ (l15 & 7)) << 4;            // ks=1: ^ 64
  const int aRd  = ((wr << 6) + l15) << 7;            // + mi*2048
  const int bRd  = 16384 + ((wc * 96 + l15) << 7);    // + ni*2048

  f32x4 acc[4][6];
#pragma unroll
  for (int i = 0; i < 4; ++i)
#pragma unroll
    for (int j = 0; j < 6; ++j) acc[i][j] = (f32x4){0.f, 0.f, 0.f, 0.f};

  bf16x8 af[4], bf[3];

  auto TILE = [&](int kt, int cb, int ob, bool st) {
    const int kn = (kt + 1) << 6;     // next tile's k element offset
    // ---- P0: ks=0, ni 0-2 ----
#pragma unroll
    for (int mi = 0; mi < 4; ++mi)
      af[mi] = *(const bf16x8*)(smem + cb + aRd + (mi << 11) + swzb);
#pragma unroll
    for (int r = 0; r < 3; ++r)
      bf[r] = *(const bf16x8*)(smem + cb + bRd + (r << 11) + swzb);
    if (st) {
      llds16(aS + kn,              smem + ob + sdst);
      llds16(aS + (1 << 17) + kn,  smem + ob + 8192 + sdst);
      llds16(bS + kn,              smem + ob + 16384 + sdst);
    }
    asm volatile("s_barrier" ::: "memory");
    __builtin_amdgcn_s_setprio(1);
#pragma unroll
    for (int mi = 0; mi < 4; ++mi)
#pragma unroll
      for (int r = 0; r < 3; ++r)
        acc[mi][r] = __builtin_amdgcn_mfma_f32_16x16x32_bf16(af[mi], bf[r], acc[mi][r], 0, 0, 0);
    __builtin_amdgcn_s_setprio(0);
    asm volatile("s_barrier" ::: "memory");
    // ---- P1: ks=0, ni 3-5 ----
#pragma unroll
    for (int r = 0; r < 3; ++r)
      bf[r] = *(const bf16x8*)(smem + cb + bRd + ((3 + r) << 11) + swzb);
    if (st) {
      llds16(bS + (1 << 17) + kn,  smem + ob + 16384 + 8192 + sdst);
      llds16(bS + (2 << 17) + kn,  smem + ob + 16384 + 16384 + sdst);
      llds16(bS + (3 << 17) + kn,  smem + ob + 16384 + 24576 + sdst);
    }
    asm volatile("s_barrier" ::: "memory");
    __builtin_amdgcn_s_setprio(1);
#pragma unroll
    for (int mi = 0; mi < 4; ++mi)
#pragma unroll
      for (int r = 0; r < 3; ++r)
        acc[mi][3 + r] = __builtin_amdgcn_mfma_f32_16x16x32_bf16(af[mi], bf[r], acc[mi][3 + r], 0, 0, 0);
    __builtin_amdgcn_s_setprio(0);
    asm volatile("s_barrier" ::: "memory");
    // ---- P2: ks=1, ni 0-2 ----
#pragma unroll
    for (int mi = 0; mi < 4; ++mi)
      af[mi] = *(const bf16x8*)(smem + cb + aRd + (mi << 11) + (swzb ^ 64));
#pragma unroll
    for (int r = 0; r < 3; ++r)
      bf[r] = *(const bf16x8*)(smem + cb + bRd + (r << 11) + (swzb ^ 64));
    if (st) {
      llds16(bS + (4 << 17) + kn,  smem + ob + 16384 + 32768 + sdst);
      llds16(bS + (5 << 17) + kn,  smem + ob + 16384 + 40960 + sdst);
    }
    asm volatile("s_barrier" ::: "memory");
    __builtin_amdgcn_s_setprio(1);
#pragma unroll
    for (int mi = 0; mi < 4; ++mi)
#pragma unroll
      for (int r = 0; r < 3; ++r)
        acc[mi][r] = __builtin_amdgcn_mfma_f32_16x16x32_bf16(af[mi], bf[r], acc[mi][r], 0, 0, 0);
    __builtin_amdgcn_s_setprio(0);
    asm volatile("s_barrier" ::: "memory");
    // ---- P3: ks=1, ni 3-5 ----
#pragma unroll
    for (int r = 0; r < 3; ++r)
      bf[r] = *(const bf16x8*)(smem + cb + bRd + ((3 + r) << 11) + (swzb ^ 64));
    asm volatile("s_barrier" ::: "memory");
    __builtin_amdgcn_s_setprio(1);
#pragma unroll
    for (int mi = 0; mi < 4; ++mi)
#pragma unroll
      for (int r = 0; r < 3; ++r)
        acc[mi][3 + r] = __builtin_amdgcn_mfma_f32_16x16x32_bf16(af[mi], bf[r], acc[mi][3 + r], 0, 0, 0);
    __builtin_amdgcn_s_setprio(0);
    asm volatile("s_barrier" ::: "memory");
    // ---- tile end: publish next tile's staging ----
    asm volatile("s_waitcnt vmcnt(0)" ::: "memory");
    asm volatile("s_barrier" ::: "memory");
  };

  // prologue: stage tile 0 into buf0
  llds16(aS, smem + sdst);
  llds16(aS + (1 << 17), smem + 8192 + sdst);
#pragma unroll
  for (int li = 0; li < 6; ++li)
    llds16(bS + li * (1 << 17), smem + 16384 + li * 8192 + sdst);
  asm volatile("s_waitcnt vmcnt(0)" ::: "memory");
  asm volatile("s_barrier" ::: "memory");

#pragma unroll 1
  for (int kt = 0; kt < 30; kt += 2) {
    TILE(kt,     0,     65536, true);
    TILE(kt + 1, 65536, 0,     true);
  }
  TILE(30, 0,     65536, true);
  TILE(31, 65536, 0,     false);

  // epilogue. C/D layout: col = lane&15, row = (lane>>4)*4 + reg  [m89]
  const float qscale = 0.02209708691207961f;   // 1/sqrt(2048)
  const int rb = q16 << 2;
#pragma unroll
  for (int mi = 0; mi < 4; ++mi) {
    int m0 = (bm << 7) + (wr << 6) + (mi << 4) + rb;
#pragma unroll
    for (int ni = 0; ni < 6; ++ni) {
      int gn = bn * 384 + wc * 96 + (ni << 4) + l15;
      int region = gn >> 11;                     // 0 Q, 1 K, 2 V
      int nloc = gn & 2047;
      if (region == 0) {
#pragma unroll
        for (int j = 0; j < 4; ++j)
          Qb[(size_t)(m0 + j) * 2048 + nloc] = f2bf(acc[mi][ni][j] * qscale);
      } else if (region == 1) {
#pragma unroll
        for (int j = 0; j < 4; ++j)
          Kb[(size_t)(m0 + j) * 2048 + nloc] = f2bf(acc[mi][ni][j]);
      } else {
        u16x4 pk;
#pragma unroll
        for (int j = 0; j < 4; ++j) pk[j] = f2bf(acc[mi][ni][j]);
        int b = m0 >> 11, t = m0 & 2047;
        *(u16x4*)(Vt + ((size_t)((b << 4) + (nloc >> 7)) * 128 + (nloc & 127)) * 2048 + t) = pk;
      }
    }
  }
}

// ---------------------------------------------------------------------------
// Wo GEMM (round-6 structure, passing): C fp32 = A[M][K] @ Bt[N][K]^T.
// BM=128, BN=128, wave tile 64x64 (2Mx2N), 4 waves, BK=32, ring-3 LDS,
// 1 barrier + vmcnt(4)/step. Grid 512 (2 blocks/CU).
// ---------------------------------------------------------------------------
__global__ __launch_bounds__(256, 2) void gemm_wo(const unsigned short* __restrict__ A,
                                                  const unsigned short* __restrict__ Bt,
                                                  float* __restrict__ Co) {
  constexpr int SLOT = 8192 + 8192;
  __shared__ __align__(16) char smem[3 * SLOT];

  const int tid  = threadIdx.x;
  const int lane = tid & 63;
  const int w    = tid >> 6;                        // 0..3
  const int q16  = lane >> 4;
  const int l15  = lane & 15;
  const int f    = blockIdx.x;
  const int g    = f >> 3;
  const int bn   = ((f & 7) << 1) + (g & 1);
  const int bm   = g >> 1;
  const int wmb  = (w >> 1) << 6;
  const int wnb  = (w & 1) << 6;

  f32x4 acc[4][4];
#pragma unroll
  for (int i = 0; i < 4; ++i)
#pragma unroll
    for (int j = 0; j < 4; ++j) acc[i][j] = (f32x4){0.f, 0.f, 0.f, 0.f};

  const int rowA = tid >> 2;
  const int chA  = tid & 3;
  auto stageT = [&](int t, char* sb) {
    const int k0 = t << 5;
#pragma unroll
    for (int r = 0; r < 2; ++r) {
      int row = (r << 6) + rowA;
      const unsigned short* src = A + (size_t)((bm << 7) + row) * 2048 + k0
                                    + ((chA ^ ((row >> 1) & 3)) << 3);
      llds16(src, sb + (r << 12) + (w << 10));
    }
#pragma unroll
    for (int r = 0; r < 2; ++r) {
      int row = (r << 6) + rowA;
      const unsigned short* src = Bt + (size_t)((bn << 7) + row) * 2048 + k0
                                     + ((chA ^ ((row >> 1) & 3)) << 3);
      llds16(src, sb + 8192 + (r << 12) + (w << 10));
    }
  };

  auto computeT = [&](const char* base) {
    bf16x8 af[4], bf[4];
#pragma unroll
    for (int mi = 0; mi < 4; ++mi) {
      int row = wmb + (mi << 4) + l15;
      af[mi] = *(const bf16x8*)(base + (row << 6) + ((q16 ^ ((row >> 1) & 3)) << 4));
    }
#pragma unroll
    for (int ni = 0; ni < 4; ++ni) {
      int row = wnb + (ni << 4) + l15;
      bf[ni] = *(const bf16x8*)(base + 8192 + (row << 6) + ((q16 ^ ((row >> 1) & 3)) << 4));
    }
    __builtin_amdgcn_s_setprio(1);
#pragma unroll
    for (int mi = 0; mi < 4; ++mi)
#pragma unroll
      for (int ni = 0; ni < 4; ++ni)
        acc[mi][ni] = __builtin_amdgcn_mfma_f32_16x16x32_bf16(af[mi], bf[ni], acc[mi][ni], 0, 0, 0);
    __builtin_amdgcn_s_setprio(0);
  };

  auto STEP = [&](int t, char* cbase, char* sbase) {
    asm volatile("s_waitcnt vmcnt(4)" ::: "memory");
    __builtin_amdgcn_s_barrier();
    stageT(t + 2, sbase);
    computeT(cbase);
  };

  char* s0 = smem;
  char* s1 = smem + SLOT;
  char* s2 = smem + 2 * SLOT;

  stageT(0, s0); stageT(1, s1);
#pragma unroll 1
  for (int t = 0; t < 60; t += 3) {
    STEP(t,     s0, s2);
    STEP(t + 1, s1, s0);
    STEP(t + 2, s2, s1);
  }
  STEP(60, s0, s2);
  STEP(61, s1, s0);
  asm volatile("s_waitcnt vmcnt(4)" ::: "memory");
  __builtin_amdgcn_s_barrier();
  computeT(s2);
  asm volatile("s_waitcnt vmcnt(0)" ::: "memory");
  __builtin_amdgcn_s_barrier();
  computeT(s0);

  const int rb = q16 << 2;
#pragma unroll
  for (int mi = 0; mi < 4; ++mi) {
    int m0 = (bm << 7) + wmb + (mi << 4) + rb;
#pragma unroll
    for (int ni = 0; ni < 4; ++ni) {
      int n = (bn << 7) + wnb + (ni << 4) + l15;
#pragma unroll
      for (int j = 0; j < 4; ++j)
        Co[(size_t)(m0 + j) * 2048 + n] = acc[mi][ni][j];
    }
  }
}

// ---------------------------------------------------------------------------
// V suffix sums at 32-row granularity.
// Suf[j][bh][d] = sum_{s >= 32j} V[b, s, h, d],  j in 0..64 (Suf[64] = 0).
// ---------------------------------------------------------------------------
__global__ __launch_bounds__(256) void vsuf_kernel(const unsigned short* __restrict__ Vt,
                                                   float* __restrict__ Suf) {
  const int row  = blockIdx.x * 4 + (threadIdx.x >> 6);  // 0..4095
  const int lane = threadIdx.x & 63;
  const unsigned short* vp = Vt + (size_t)row * 2048 + (lane << 5);
  float a = 0.f;
#pragma unroll
  for (int c = 0; c < 4; ++c) {
    bf16x8 v = *(const bf16x8*)(vp + (c << 3));
#pragma unroll
    for (int j = 0; j < 8; ++j) a += bf2f((unsigned short)v[j]);
  }
  float I = a;
#pragma unroll
  for (int off = 1; off < 64; off <<= 1) {
    float t = __shfl_down(I, off, 64);
    I += (lane + off < 64) ? t : 0.f;
  }
  Suf[(size_t)lane * 4096 + row] = I;
  if (lane == 0) Suf[(size_t)64 * 4096 + row] = 0.f;
}

// ---------------------------------------------------------------------------
// Fused attention, causal-skipped. Flat grid 1024; decode:
//   xcd = f&7, bh = xcd*4 + ((f>>3)&3), strip = 31 - (f>>5)  (LPT order)
// Q is PRE-SCALED by 1/sqrt(T). Mask only on the straddling tile. Tiles
// above the diagonal covered by V-suffix sums (p == 1 exactly there).
// ---------------------------------------------------------------------------
__global__ __launch_bounds__(256) void attn_kernel(const unsigned short* __restrict__ Q,
                                                   const unsigned short* __restrict__ K,
                                                   const unsigned short* __restrict__ V,  // Vt layout
                                                   const float* __restrict__ Suf,
                                                   unsigned short* __restrict__ O) {
  __shared__ __align__(16) char smem[36864];  // K dbuf 2x8K | V dbuf 2x8K | P 4x1K
  const int tid  = threadIdx.x;
  const int lane = tid & 63;
  const int w    = tid >> 6;
  const int q16  = lane >> 4;
  const int l15  = lane & 15;
  const int f    = blockIdx.x;
  const int bh    = ((f & 7) << 2) + ((f >> 3) & 3);
  const int strip = 31 - (f >> 5);
  const int b  = bh >> 4;
  const size_t qkbase = ((size_t)(b << 11)) * 2048 + ((size_t)(bh & 15) << 7);
  const size_t vbase  = (size_t)bh << 18;     // bh*128*2048
  const int rb = q16 << 2;
  char* Psm = smem + 32768 + (w << 10);

  const int numIter = 2 * strip + 2;
  const int t0 = (strip << 6) + (w << 4);

  auto stage = [&](int s0, int kb, int vb) {
#pragma unroll
    for (int c = 0; c < 2; ++c) {
      int ch = (w << 1) + c;
      int rowK = (ch << 2) + q16;                        // 4 rows / 1KB chunk
      int colbK = (l15 << 4) ^ ((rowK & 7) << 4);
      llds16(K + qkbase + (size_t)(s0 + rowK) * 2048 + (colbK >> 1), smem + kb + (ch << 10));
      int rowV = (ch << 4) + (lane >> 2);                // 16 rows / 1KB chunk
      int colbV = ((lane & 3) << 4) ^ (((rowV >> 2) & 3) << 4);
      llds16(V + vbase + (size_t)rowV * 2048 + s0 + (colbV >> 1), smem + vb + (ch << 10));
    }
  };

  // Q fragments: lane holds Q[t0 + (lane&15)][8*(lane>>4) + j + 32*kk]
  bf16x8 qf[4];
  {
    const unsigned short* qp = Q + qkbase + (size_t)(t0 + l15) * 2048 + (q16 << 3);
#pragma unroll
    for (int kk = 0; kk < 4; ++kk) qf[kk] = *(const bf16x8*)(qp + (kk << 5));
  }

  f32x4 oacc[8];
#pragma unroll
  for (int i = 0; i < 8; ++i) oacc[i] = (f32x4){0.f, 0.f, 0.f, 0.f};
  float ell[4] = {0.f, 0.f, 0.f, 0.f};   // per-lane partial; reduced in epilogue

  stage(0, 0, 16384);
  asm volatile("s_waitcnt vmcnt(0)" ::: "memory");
  __syncthreads();

  int cur = 0;
  for (int it = 0; it < numIter; ++it) {
    const int s0 = it << 5;
    if (it + 1 < numIter)
      stage(s0 + 32, (cur ^ 1) << 13, 16384 + ((cur ^ 1) << 13));

    if (s0 <= t0) {   // tile not entirely above this wave's diagonal
      const int kb = cur << 13;
      const int vb = 16384 + (cur << 13);

      // QK^T: two 16-col s-tiles (scores already scaled via Q)
      f32x4 sA = (f32x4){0.f, 0.f, 0.f, 0.f}, sB = (f32x4){0.f, 0.f, 0.f, 0.f};
#pragma unroll
      for (int kk = 0; kk < 4; ++kk) {
        int r0 = l15;
        bf16x8 k0f = *(const bf16x8*)(smem + kb + (r0 << 8) + (((kk << 6) + (q16 << 4)) ^ ((r0 & 7) << 4)));
        sA = __builtin_amdgcn_mfma_f32_16x16x32_bf16(qf[kk], k0f, sA, 0, 0, 0);
        int r1 = 16 + l15;
        bf16x8 k1f = *(const bf16x8*)(smem + kb + (r1 << 8) + (((kk << 6) + (q16 << 4)) ^ ((r1 & 7) << 4)));
        sB = __builtin_amdgcn_mfma_f32_16x16x32_bf16(qf[kk], k1f, sB, 0, 0, 0);
      }

      float pA[4], pB[4];
      if (s0 + 31 <= t0) {           // fully unmasked tile (the common case)
#pragma unroll
        for (int j = 0; j < 4; ++j) {
          pA[j] = __expf(sA[j]);
          pB[j] = __expf(sB[j]);
          ell[j] += pA[j] + pB[j];
        }
      } else {                       // straddling tile: mask -> exp(0)=1
#pragma unroll
        for (int j = 0; j < 4; ++j) {
          int t  = t0 + rb + j;
          int sa = s0 + l15;
          float vA = (sa <= t)      ? sA[j] : 0.f;
          float vB = (sa + 16 <= t) ? sB[j] : 0.f;
          pA[j] = __expf(vA);
          pB[j] = __expf(vB);
          ell[j] += pA[j] + pB[j];
        }
      }

      // P -> per-wave LDS [16 t][32 s] bf16, swz: col ^= ((row>>1)&3)<<4
#pragma unroll
      for (int j = 0; j < 4; ++j) {
        int r   = rb + j;
        int swz = ((r >> 1) & 3) << 4;
        *(unsigned short*)(Psm + (r << 6) + ((l15 << 1) ^ swz))        = f2bfru(pA[j]);
        *(unsigned short*)(Psm + (r << 6) + ((32 + (l15 << 1)) ^ swz)) = f2bfru(pB[j]);
      }
      asm volatile("s_waitcnt lgkmcnt(0)" ::: "memory");

      bf16x8 pa;
      {
        int r = l15;
        pa = *(const bf16x8*)(Psm + (r << 6) + ((q16 << 4) ^ (((r >> 1) & 3) << 4)));
      }
#pragma unroll
      for (int ni = 0; ni < 8; ++ni) {
        int dr = (ni << 4) + l15;
        bf16x8 vbf = *(const bf16x8*)(smem + vb + (dr << 6) + ((q16 << 4) ^ (((dr >> 2) & 3) << 4)));
        oacc[ni] = __builtin_amdgcn_mfma_f32_16x16x32_bf16(pa, vbf, oacc[ni], 0, 0, 0);
      }
    }

    asm volatile("s_waitcnt vmcnt(0)" ::: "memory");
    __syncthreads();
    cur ^= 1;
  }

  // suffix correction: all s >= send have p == 1 exactly.
  const int send = (t0 & ~31) + 32;
  const float* sp = Suf + (size_t)(send >> 5) * 4096 + ((size_t)bh << 7);
  const float extra = (float)(2048 - send);
#pragma unroll
  for (int ni = 0; ni < 8; ++ni) {
    float sv = sp[(ni << 4) + l15];
#pragma unroll
    for (int j = 0; j < 4; ++j) oacc[ni][j] += sv;
  }

  // deferred ell reduction (within each 16-lane row group), then normalize
#pragma unroll
  for (int j = 0; j < 4; ++j) {
    float r = ell[j];
    r += __shfl_xor(r, 1, 64);
    r += __shfl_xor(r, 2, 64);
    r += __shfl_xor(r, 4, 64);
    r += __shfl_xor(r, 8, 64);
    float inv = 1.0f / (r + extra);
    int t = t0 + rb + j;
    unsigned short* op = O + qkbase + (size_t)t * 2048;
#pragma unroll
    for (int ni = 0; ni < 8; ++ni)
      op[(ni << 4) + l15] = f2bf(oacc[ni][j] * inv);
  }
}

// ---------------------------------------------------------------------------
// launch
// ---------------------------------------------------------------------------
extern "C" void kernel_launch(void* const* d_in, const int* in_sizes, int n_in,
                              void* d_out, int out_size, void* d_ws, size_t ws_size,
                              hipStream_t stream) {
  (void)in_sizes; (void)n_in; (void)out_size; (void)ws_size;
  const float* x  = (const float*)d_in[0];
  const float* Wq = (const float*)d_in[1];
  const float* Wk = (const float*)d_in[2];
  const float* Wv = (const float*)d_in[3];
  const float* Wo = (const float*)d_in[4];
  float* out = (float*)d_out;

  char* ws = (char*)d_ws;
  unsigned short* Xb  = (unsigned short*)(ws);                        // 16 MiB (reused as O)
  unsigned short* Wqt = (unsigned short*)(ws + 16777216);             // 8 MiB (reused as Suf)
  unsigned short* Wkt = (unsigned short*)(ws + 16777216 + 8388608);
  unsigned short* Wvt = (unsigned short*)(ws + 16777216 + 2 * 8388608);
  unsigned short* Wot = (unsigned short*)(ws + 16777216 + 3 * 8388608);
  unsigned short* Qb  = (unsigned short*)(ws + 50331648);             // 16 MiB
  unsigned short* Kb  = (unsigned short*)(ws + 67108864);             // 16 MiB
  unsigned short* Vt  = (unsigned short*)(ws + 83886080);             // 16 MiB
  unsigned short* Ob  = Xb;          // X dead after the QKV projection
  float*          Suf = (float*)Wqt; // W^T dead after the QKV projection

  cast_x_kernel<<<8192, 256, 0, stream>>>(x, Xb);
  {
    dim3 tb(32, 8), tg(64, 64, 4);
    transpose_w4_kernel<<<tg, tb, 0, stream>>>(Wq, Wk, Wv, Wo, Wqt, Wkt, Wvt, Wot);
  }
  // fused QKV projection: Bt = [Wqt|Wkt|Wvt] (contiguous), N=6144
  gemm_qkv8<<<512, 512, 0, stream>>>(Xb, Wqt, Qb, Kb, Vt);

  vsuf_kernel<<<1024, 256, 0, stream>>>(Vt, Suf);

  attn_kernel<<<1024, 256, 0, stream>>>(Qb, Kb, Vt, Suf, Ob);

  gemm_wo<<<512, 256, 0, stream>>>(Ob, Wot, out);
}